// Round 8
// baseline (895.874 us; speedup 1.0000x reference)
//
#include <hip/hip_runtime.h>
#include <math.h>

// Problem dims
#define BB 32
#define NN 32
#define EE 256
#define HH 1500
#define G4 6000      // 4*HH
#define QIN 512
#define Q1O 600
#define QO 300
#define EV1 1000
#define EV2 100
#define EV3 10
#define PP 496       // N*(N-1)/2
#define ROWS (BB*PP) // 15872
#define BH (BB*HH)   // 48000

// Packed GEMM operand tile: [planes][128 rows][40 shorts]; plane = 5120 shorts
#define TROW 40
#define TPLANE (128 * TROW)   // 5120 shorts per plane

// LSTM fused geometry: 375 blocks x 4 h-indices, K padded to 47*32=1504
#define LKT 47
#define LBLK 375
#define LTILE 2048            // h-buffer shorts per kt: [2 planes][32 rows][32 k]
#define HSZ (LKT * LTILE)     // 96256 shorts per h buffer
#define LTILE_W 512           // wf shorts per (blk,kt): [16 rows][32 k] single plane
#define HSZW (LKT * LTILE_W)  // 24064 shorts per block slice

typedef __attribute__((ext_vector_type(8))) short bf16x8;
typedef __attribute__((ext_vector_type(4))) float f32x4;

__device__ __forceinline__ float sigm(float x) { return 1.f / (1.f + expf(-x)); }

// RNE round to bf16, kept as fp32 bit pattern (low 16 bits zero)
__device__ __forceinline__ unsigned bf16h(float x) {
    unsigned u = __float_as_uint(x);
    return (u + 0x7FFFu + ((u >> 16) & 1u)) & 0xFFFF0000u;
}

// split float4 -> hi/lo bf16 quads, 8B store each
__device__ __forceinline__ void split4(float4 v, short* hp, short* lp) {
    unsigned h0 = bf16h(v.x), h1 = bf16h(v.y), h2 = bf16h(v.z), h3 = bf16h(v.w);
    float r0 = v.x - __uint_as_float(h0);
    float r1 = v.y - __uint_as_float(h1);
    float r2 = v.z - __uint_as_float(h2);
    float r3 = v.w - __uint_as_float(h3);
    unsigned l0 = bf16h(r0), l1 = bf16h(r1), l2 = bf16h(r2), l3 = bf16h(r3);
    uint2 hw, lw;
    hw.x = (h0 >> 16) | (h1 & 0xFFFF0000u);
    hw.y = (h2 >> 16) | (h3 & 0xFFFF0000u);
    lw.x = (l0 >> 16) | (l1 & 0xFFFF0000u);
    lw.y = (l2 >> 16) | (l3 & 0xFFFF0000u);
    *(uint2*)hp = hw;
    *(uint2*)lp = lw;
}

// hi-plane only version (pure bf16)
__device__ __forceinline__ void hi4(float4 v, short* hp) {
    unsigned h0 = bf16h(v.x), h1 = bf16h(v.y), h2 = bf16h(v.z), h3 = bf16h(v.w);
    uint2 hw;
    hw.x = (h0 >> 16) | (h1 & 0xFFFF0000u);
    hw.y = (h2 >> 16) | (h3 & 0xFFFF0000u);
    *(uint2*)hp = hw;
}

// async 16B global -> LDS (dest wave-uniform; HW adds lane*16B)
#define ASYNC16(dst, src) \
    __builtin_amdgcn_global_load_lds((const __attribute__((address_space(1))) unsigned*)(src), \
                                     (__attribute__((address_space(3))) unsigned*)(dst), 16, 0, 0)

// ---------------- init helpers ----------------
__global__ void k_zero(float* a, int n) {
    int i = blockIdx.x * 256 + threadIdx.x;
    if (i < n) a[i] = 0.f;
}

__global__ void k_iijj(int* iijj) {
    int p = threadIdx.x;
    if (p >= PP) return;
    int i = 0, p0 = 0;
    while (p >= p0 + (NN - 1 - i)) { p0 += NN - 1 - i; i++; }
    iijj[p] = i;
    iijj[PP + p] = i + 1 + (p - p0);
}

// q1 effective bias: q1_b[o] + sum over odd k of q1_w[o][k]  (PE at pos 0)
__global__ void k_q1beff(const float* q1w, const float* q1b, float* beff) {
    int o = blockIdx.x * 256 + threadIdx.x;
    if (o >= Q1O) return;
    float a = q1b[o];
    for (int k = 1; k < QIN; k += 2) a += q1w[o * QIN + k];
    beff[o] = a;
}

__global__ void k_addb(const float* a, const float* b, float* c, int n) {
    int i = blockIdx.x * 256 + threadIdx.x;
    if (i < n) c[i] = a[i] + b[i];
}

// ---------------- transpose (sub-range of columns) ----------------
__global__ void k_transpose(const float* __restrict__ src, float* __restrict__ dst,
                            int R, int C, int c0, int csub) {
    __shared__ float tile[32][33];
    int cb = blockIdx.x * 32, rb = blockIdx.y * 32;
    for (int dy = threadIdx.y; dy < 32; dy += 8) {
        int r = rb + dy, c = cb + threadIdx.x;
        if (r < R && c < csub) tile[dy][threadIdx.x] = src[(size_t)r * C + c0 + c];
    }
    __syncthreads();
    for (int dy = threadIdx.y; dy < 32; dy += 8) {
        int c = cb + dy, r = rb + threadIdx.x;
        if (c < csub && r < R) dst[(size_t)c * R + r] = tile[threadIdx.x][dy];
    }
}

// ---------------- pack fp32 [NR x K from col0] -> blocked bf16 hi/lo tiles ----------------
// dst: [mt][kt][2][128][40] shorts. gridDim.x = KT, gridDim.y = ceil(NR/128). Pads zeroed.
__global__ void k_pack(const float* __restrict__ src, int ld, int col0, int NR, int K,
                       short* __restrict__ D) {
    int kt = blockIdx.x, mt = blockIdx.y, KT = gridDim.x;
    size_t tb = ((size_t)mt * KT + kt) * (2 * TPLANE);
    for (int idx = threadIdx.x; idx < 1024; idx += 256) {
        int rowin = idx >> 3, k4 = (idx & 7) << 2;
        int r = mt * 128 + rowin, k = kt * 32 + k4;
        float4 v = {0.f, 0.f, 0.f, 0.f};
        if (r < NR && k < K) v = *(const float4*)(src + (size_t)r * ld + col0 + k);
        size_t o = tb + rowin * TROW + k4;
        split4(v, D + o, D + o + TPLANE);
    }
}

// ---------------- pack w_hh gate-interleaved, PURE bf16, for fused LSTM ----------------
// wf[blk 375][kt 47][16 rows][32 k] shorts. row = h_loc*4 + gate,
// h_glob = blk*4 + h_loc. K pads zero.
__global__ void k_pack_wf(const float* __restrict__ whh, short* __restrict__ wf) {
    int kt = blockIdx.x, blk = blockIdx.y;
    size_t tb = ((size_t)blk * LKT + kt) * LTILE_W;
    int t = threadIdx.x;                  // 128 threads: one float4 each
    int row = t >> 3, k4 = (t & 7) << 2;
    int g = row & 3, h_glob = blk * 4 + (row >> 2);
    int k = kt * 32 + k4;
    float4 v = {0.f, 0.f, 0.f, 0.f};
    if (k < HH) {
        int j = g * HH + h_glob;
        v = *(const float4*)(whh + (size_t)j * HH + k);
    }
    hi4(v, wf + tb + row * 32 + k4);
}

// ---------------- sort along parts axis: bitonic network (static indices) ----------------
__global__ void k_sort(const float* __restrict__ x, float* __restrict__ seq) {
    int tid = blockIdx.x * 256 + threadIdx.x;
    if (tid >= BB * EE) return;
    int b = tid / EE, e = tid % EE;
    float v[NN];
#pragma unroll
    for (int n = 0; n < NN; n++) v[n] = x[(b * NN + n) * EE + e];
#pragma unroll
    for (int kk = 2; kk <= NN; kk <<= 1) {
#pragma unroll
        for (int jj = kk >> 1; jj > 0; jj >>= 1) {
#pragma unroll
            for (int i = 0; i < NN; i++) {
                int l = i ^ jj;
                if (l > i) {
                    bool up = (i & kk) == 0;
                    float a = v[i], c = v[l];
                    bool sw = up ? (a > c) : (a < c);
                    float lo = sw ? c : a, hi = sw ? a : c;
                    v[i] = lo; v[l] = hi;
                }
            }
        }
    }
#pragma unroll
    for (int n = 0; n < NN; n++) seq[(n * BB + b) * EE + e] = v[n];
}

// ---------------- pairs gather, writes packed bf16 hi/lo tiles directly ----------------
__global__ void k_pairs(const float* __restrict__ x, const int* __restrict__ iijj,
                        short* __restrict__ P) {
    int idx = blockIdx.x * 256 + threadIdx.x; // quad index
    int r = idx >> 7;
    if (r >= ROWS) return;
    int q = idx & 127, k = q << 2;
    int b = r / PP, p = r - b * PP;
    int part = (k < EE) ? iijj[p] : iijj[PP + p];
    float4 v = *(const float4*)(x + (size_t)(b * NN + part) * EE + (k & (EE - 1)));
    int mt = r >> 7, rowin = r & 127, kt = k >> 5, k4 = k & 31;
    size_t o = ((size_t)mt * 16 + kt) * (2 * TPLANE) + rowin * TROW + k4;
    split4(v, P + o, P + o + TPLANE);
}

// ---------------- templated MFMA GEMM ----------------
// APL: A planes (2 = hi/lo bf16x3, 1 = pure bf16). PPL: pack-out planes.
// B always hi/lo. XCD-grouped 1D grid: grid = 8 * NT * ceil(MT/8).
// cmode 0: C[row][col] = act(acc + bias[col] + pbm). cmode 1: transposed xgT write,
// xgT[(col>>5)*G4*32 + row*32 + (col&31)] = acc + bias[row], guarded row < G4.
// Pack-out written unguarded (cols >= N compute exact 0 from zero-padded B).
template<int APL, int PPL>
__global__ __launch_bounds__(256, 2)
void k_gemm_t(const short* __restrict__ Ap, int AKT, const short* __restrict__ Bp,
              const float* __restrict__ bias, const float* __restrict__ pbm,
              float* __restrict__ Cf32, short* __restrict__ P, int PKT,
              int M, int K, int N, int relu, int cmode) {
    const int ATS = APL * TPLANE;          // A tile shorts
    const int BTS = 2 * TPLANE;            // B tile shorts
    __shared__ __align__(16) short lds[2][APL * TPLANE + 2 * TPLANE];

    int MT = M >> 7, NT = (N + 127) >> 7;
    int bid = blockIdx.x;
    int xcd = bid & 7, rr = bid >> 3;
    int nt = rr % NT, mtc = rr / NT;
    int mt = mtc * 8 + xcd;
    if (mt >= MT) return;

    int tid = threadIdx.x;
    int lane = tid & 63, w = tid >> 6;
    int wr = w >> 1, wc = w & 1;
    int ksteps = (K + 31) >> 5;

    const short* gA = Ap + (size_t)mt * AKT * ATS;
    const short* gB = Bp + (size_t)nt * ksteps * BTS;

#define STAGE(bufi, kt) do { \
        const short* sa_ = gA + (size_t)(kt) * ATS + lane * 8; \
        const short* sb_ = gB + (size_t)(kt) * BTS + lane * 8; \
        for (int c_ = w; c_ < ATS / 512; c_ += 4) \
            ASYNC16(&lds[bufi][c_ * 512], sa_ + c_ * 512); \
        for (int c_ = w; c_ < BTS / 512; c_ += 4) \
            ASYNC16(&lds[bufi][ATS + c_ * 512], sb_ + c_ * 512); \
    } while (0)

    f32x4 acc[4][4];
#pragma unroll
    for (int mi = 0; mi < 4; mi++)
#pragma unroll
        for (int ni = 0; ni < 4; ni++) acc[mi][ni] = (f32x4){0.f, 0.f, 0.f, 0.f};

    int l15 = lane & 15;
    int kc8 = (lane >> 4) << 3;

    STAGE(0, 0);
    __syncthreads();

    int buf = 0;
    for (int kt = 0; kt < ksteps; kt++) {
        if (kt + 1 < ksteps) STAGE(buf ^ 1, kt + 1);

        const short* LA = &lds[buf][0];
        const short* LB = &lds[buf][ATS];

        bf16x8 ah[4], al[4];
#pragma unroll
        for (int mi = 0; mi < 4; mi++) {
            int o = (wr * 64 + mi * 16 + l15) * TROW + kc8;
            ah[mi] = *(const bf16x8*)(LA + o);
            if constexpr (APL == 2) al[mi] = *(const bf16x8*)(LA + TPLANE + o);
        }
#pragma unroll
        for (int ni = 0; ni < 4; ni++) {
            int o = (wc * 64 + ni * 16 + l15) * TROW + kc8;
            bf16x8 bh = *(const bf16x8*)(LB + o);
            bf16x8 bl = *(const bf16x8*)(LB + TPLANE + o);
#pragma unroll
            for (int mi = 0; mi < 4; mi++) {
                acc[mi][ni] = __builtin_amdgcn_mfma_f32_16x16x32_bf16(ah[mi], bh, acc[mi][ni], 0, 0, 0);
                acc[mi][ni] = __builtin_amdgcn_mfma_f32_16x16x32_bf16(ah[mi], bl, acc[mi][ni], 0, 0, 0);
                if constexpr (APL == 2)
                    acc[mi][ni] = __builtin_amdgcn_mfma_f32_16x16x32_bf16(al[mi], bh, acc[mi][ni], 0, 0, 0);
            }
        }
        __syncthreads();
        buf ^= 1;
    }
#undef STAGE

    const int PTS = PPL * TPLANE;
#pragma unroll
    for (int ni = 0; ni < 4; ni++) {
        int col = nt * 128 + wc * 64 + ni * 16 + l15;
        float bb = (cmode == 0 && bias && col < N) ? bias[col] : 0.f;
#pragma unroll
        for (int mi = 0; mi < 4; mi++) {
            int rbase = mt * 128 + wr * 64 + mi * 16 + ((lane >> 4) << 2);
#pragma unroll
            for (int r4 = 0; r4 < 4; r4++) {
                int row = rbase + r4;
                float v = acc[mi][ni][r4];
                if (cmode == 1) {
                    if (row < G4)
                        Cf32[(size_t)(col >> 5) * (G4 * BB) + (size_t)row * BB + (col & 31)]
                            = v + bias[row];
                    continue;
                }
                v += bb;
                if (pbm && col < N) v += pbm[(size_t)(row / PP) * N + col];
                if (relu) v = fmaxf(v, 0.f);
                if (Cf32 && col < N) Cf32[(size_t)row * N + col] = v;
                if (P) {
                    unsigned h = bf16h(v);
                    int kt2 = col >> 5, kin = col & 31, rowin = row & 127, mtt = row >> 7;
                    size_t o = ((size_t)mtt * PKT + kt2) * PTS + rowin * TROW + kin;
                    P[o] = (short)(h >> 16);
                    if constexpr (PPL == 2) {
                        unsigned l = bf16h(v - __uint_as_float(h));
                        P[o + TPLANE] = (short)(l >> 16);
                    }
                }
            }
        }
    }
}

// ---------------- fused LSTM step: 375 blocks x 4 waves, k-split 2-way ----------------
// Block owns h [blk*4, blk*4+4). wave = (ks, mi): ks halves kt range (chain 47 -> 24),
// LDS-reduce ks=1 partials into ks=0; mi = batch half. acc init = xgT preactivation.
// h in hi/lo bf16 planes; weights PURE bf16 (18 MB, L2-resident across steps).
// 4-lane shuffle gathers gates i,f,g,o; owner lanes update c and write h.
__global__ __launch_bounds__(256, 1)
void k_lstm_step(const short* __restrict__ wf, const short* __restrict__ hbuf_r,
                 short* __restrict__ hbuf_w, const float* __restrict__ xgT_n,
                 float* __restrict__ ct, float* __restrict__ ht) {
    __shared__ f32x4 red[2][64];
    int tid = threadIdx.x, lane = tid & 63, wave = tid >> 6;
    int ks = wave >> 1, mi = wave & 1;
    int blk = blockIdx.x;
    int l15 = lane & 15, bg = lane >> 4;
    int kc8 = bg << 3;
    int n = l15, g = n & 3;
    int h_glob = blk * 4 + (n >> 2);
    int kt0 = ks * 24, ktend = ks ? LKT : 24;

    f32x4 accA = {0.f, 0.f, 0.f, 0.f}, accB = {0.f, 0.f, 0.f, 0.f};
    if (ks == 0)
        accA = *(const f32x4*)(xgT_n + (size_t)(g * HH + h_glob) * BB + mi * 16 + bg * 4);

    const short* wp0 = wf + (size_t)blk * HSZW + l15 * 32 + kc8;
    const short* hp0 = hbuf_r + (mi * 16 + l15) * 32 + kc8;

    // depth-3 software pipeline, named-register rotation
    bf16x8 a0h = *(const bf16x8*)(hp0 + (size_t)kt0 * LTILE);
    bf16x8 a0l = *(const bf16x8*)(hp0 + (size_t)kt0 * LTILE + 1024);
    bf16x8 b0  = *(const bf16x8*)(wp0 + (size_t)kt0 * LTILE_W);
    bf16x8 a1h = *(const bf16x8*)(hp0 + (size_t)(kt0 + 1) * LTILE);
    bf16x8 a1l = *(const bf16x8*)(hp0 + (size_t)(kt0 + 1) * LTILE + 1024);
    bf16x8 b1  = *(const bf16x8*)(wp0 + (size_t)(kt0 + 1) * LTILE_W);
    bf16x8 a2h = *(const bf16x8*)(hp0 + (size_t)(kt0 + 2) * LTILE);
    bf16x8 a2l = *(const bf16x8*)(hp0 + (size_t)(kt0 + 2) * LTILE + 1024);
    bf16x8 b2  = *(const bf16x8*)(wp0 + (size_t)(kt0 + 2) * LTILE_W);
    for (int kt = kt0; kt < ktend; kt++) {
        bf16x8 a3h, a3l, b3;
        if (kt + 3 < ktend) {
            const short* hp = hp0 + (size_t)(kt + 3) * LTILE;
            const short* wp = wp0 + (size_t)(kt + 3) * LTILE_W;
            a3h = *(const bf16x8*)(hp);
            a3l = *(const bf16x8*)(hp + 1024);
            b3  = *(const bf16x8*)(wp);
        }
        accA = __builtin_amdgcn_mfma_f32_16x16x32_bf16(a0h, b0, accA, 0, 0, 0);
        accB = __builtin_amdgcn_mfma_f32_16x16x32_bf16(a0l, b0, accB, 0, 0, 0);
        a0h = a1h; a0l = a1l; b0 = b1;
        a1h = a2h; a1l = a2l; b1 = b2;
        a2h = a3h; a2l = a3l; b2 = b3;
    }
    f32x4 acc = accA + accB;

    // reduce ks=1 partials into ks=0 waves
    if (ks == 1) red[mi][lane] = acc;
    __syncthreads();
    if (ks == 1) return;
    acc += red[mi][lane];

    // gather the 4 gates across the 4-lane group (lane n, n^1, n^2, n^3)
    float gg[4][4];
#pragma unroll
    for (int r = 0; r < 4; r++) {
        float a = acc[r];
        gg[0][r] = a;
        gg[1][r] = __shfl_xor(a, 1);
        gg[2][r] = __shfl_xor(a, 2);
        gg[3][r] = __shfl_xor(a, 3);
    }

    if ((n & 3) == 0) {
        int kth = h_glob >> 5, kin = h_glob & 31;
#pragma unroll
        for (int r = 0; r < 4; r++) {
            int b = mi * 16 + bg * 4 + r;
            float ci = ct[h_glob * BB + b];
            float cn = sigm(gg[1][r]) * ci + sigm(gg[0][r]) * tanhf(gg[2][r]);
            ct[h_glob * BB + b] = cn;
            float hv = sigm(gg[3][r]) * tanhf(cn);
            ht[h_glob * BB + b] = hv;
            unsigned hh = bf16h(hv);
            unsigned hl = bf16h(hv - __uint_as_float(hh));
            size_t o = (size_t)kth * LTILE + b * 32 + kin;
            hbuf_w[o] = (short)(hh >> 16);
            hbuf_w[o + 1024] = (short)(hl >> 16);
        }
    }
}

// ---------------- plan-side e1 bias (plan in ht layout [h][b]) ----------------
__global__ void k_pb(const float* __restrict__ ht, const float* __restrict__ e1at,
                     const float* __restrict__ e1b, float* __restrict__ pb) {
    __shared__ float ps[HH];
    int b = blockIdx.y;
    for (int idx = threadIdx.x; idx < HH; idx += 256) ps[idx] = ht[(size_t)idx * BB + b];
    __syncthreads();
    int o = blockIdx.x * 256 + threadIdx.x;
    if (o >= EV1) return;
    float acc = e1b[o];
    for (int k = 0; k < HH; k++) acc += ps[k] * e1at[(size_t)k * EV1 + o];
    pb[b * EV1 + o] = acc;
}

// ---------------- fused e3 + e4 tail ----------------
__global__ void k_e34(const float* __restrict__ e2out, const float* __restrict__ e3t,
                      const float* __restrict__ e3b, const float* __restrict__ e4w,
                      const float* __restrict__ e4b, float* __restrict__ out) {
    __shared__ float wt[EV2 * EV3];
    for (int idx = threadIdx.x; idx < EV2 * EV3; idx += 256) wt[idx] = e3t[idx];
    __syncthreads();
    int r = blockIdx.x * 256 + threadIdx.x;
    if (r >= ROWS) return;
    float h3[EV3];
#pragma unroll
    for (int o3 = 0; o3 < EV3; o3++) h3[o3] = e3b[o3];
    for (int k = 0; k < EV2; k++) {
        float v = e2out[(size_t)r * EV2 + k];
#pragma unroll
        for (int o3 = 0; o3 < EV3; o3++) h3[o3] += v * wt[k * EV3 + o3];
    }
    float acc = e4b[0];
#pragma unroll
    for (int o3 = 0; o3 < EV3; o3++) acc += fmaxf(h3[o3], 0.f) * e4w[o3];
    out[r] = fmaxf(acc, 0.f);
}

// ---------------- host launch ----------------
extern "C" void kernel_launch(void* const* d_in, const int* in_sizes, int n_in,
                              void* d_out, int out_size, void* d_ws, size_t ws_size,
                              hipStream_t stream) {
    const float* x    = (const float*)d_in[0];
    const float* w_ih = (const float*)d_in[1];
    const float* w_hh = (const float*)d_in[2];
    const float* b_ih = (const float*)d_in[3];
    const float* b_hh = (const float*)d_in[4];
    const float* q1_w = (const float*)d_in[5];
    const float* q1_b = (const float*)d_in[6];
    const float* q2_w = (const float*)d_in[7];
    const float* q2_b = (const float*)d_in[8];
    const float* e1_w = (const float*)d_in[9];
    const float* e1_b = (const float*)d_in[10];
    const float* e2_w = (const float*)d_in[11];
    const float* e2_b = (const float*)d_in[12];
    const float* e3_w = (const float*)d_in[13];
    const float* e3_b = (const float*)d_in[14];
    const float* e4_w = (const float*)d_in[15];
    const float* e4_b = (const float*)d_in[16];
    float* out = (float*)d_out;
    float* ws = (float*)d_ws;

    // ---- workspace layout (float offsets) ----
    // regionA (23M floats), phase-aliased:
    //  pack/xg : wf [0,4.52M) | seq_p [4.6M,4.93M) | wih_p [5.0M,6.93M)
    //  LSTM    : wf [0,4.52M)
    //  q1      : pairs_p [0,10.16M) | q1out_p [10.2M,16.55M)   (wf/seq_p/wih_p dead)
    //  e1      : e1out_p [0,10.16M)  (pairs_p dead; q1out_p dead after q2)
    //  e2      : e1out_p | e2out [20.4M,21.99M)
    size_t off = 0;
    float* seq    = ws + off; off += (size_t)NN * BB * EE;   // 262,144
    size_t regionA = off; off += 23000000;
    short* wf       = (short*)(ws + regionA);                // 375*47*512 = 9,024,000 sh
    short* seq_p    = (short*)(ws + regionA + 4600000);      // 655,360 sh
    short* wih_p    = (short*)(ws + regionA + 5000000);      // 3,850,240 sh
    short* pairs_p  = (short*)(ws + regionA);                // 20,316,160 sh (hi/lo)
    short* q1out_p  = (short*)(ws + regionA + 10200000);     // 12,697,600 sh (bf16)
    short* e1out_p  = (short*)(ws + regionA);                // 20,316,160 sh (bf16)
    float* e2out    = ws + regionA + 20400000;               // 1,587,200 fl
    float* xgT    = ws + off; off += 7618560;                // 6,144,000 fl; q2out_p alias
    short* q2out_p  = (short*)xgT;                           // 7,618,560 sh (bf16)
    float* ht     = ws + off; off += BH;
    float* ct     = ws + off; off += BH;
    short* hbuf   = (short*)(ws + off); off += 96256;        // 2 x HSZ shorts
    short* q1w_p  = (short*)(ws + off); off += 409600;
    short* q2w_p  = (short*)(ws + off); off += 291840;
    short* e1w_p  = (short*)(ws + off); off += 409600;
    short* e2w_p  = (short*)(ws + off); off += 163840;
    float* e1at   = ws + off; off += (size_t)HH * EV1;
    float* e3t    = ws + off; off += 1024;
    float* pb     = ws + off; off += BB * EV1;
    float* q1beff = ws + off; off += 1024;
    float* bsum   = ws + off; off += 6016;
    int*   iijj   = (int*)(ws + off); off += 1024;

    dim3 tb(32, 8);

    // init
    k_iijj<<<1, 512, 0, stream>>>(iijj);
    k_q1beff<<<3, 256, 0, stream>>>(q1_w, q1_b, q1beff);
    k_addb<<<24, 256, 0, stream>>>(b_ih, b_hh, bsum, G4);
    k_zero<<<188, 256, 0, stream>>>(ct, BH);
    k_zero<<<376, 256, 0, stream>>>((float*)hbuf, 96256);

    // weight transforms
    k_pack_wf<<<dim3(LKT, LBLK), 128, 0, stream>>>(w_hh, wf);
    k_transpose<<<dim3(47, 32), tb, 0, stream>>>(e1_w, e1at, EV1, HH + QO, 0, HH);
    k_transpose<<<dim3(4, 1), tb, 0, stream>>>(e3_w, e3t, EV3, EV2, 0, EV2);
    k_pack<<<dim3(8, 47), 256, 0, stream>>>(w_ih, EE, 0, G4, EE, wih_p);
    k_pack<<<dim3(16, 5), 256, 0, stream>>>(q1_w, QIN, 0, Q1O, QIN, q1w_p);
    k_pack<<<dim3(19, 3), 256, 0, stream>>>(q2_w, Q1O, 0, QO, Q1O, q2w_p);
    k_pack<<<dim3(10, 8), 256, 0, stream>>>(e1_w, HH + QO, HH, EV1, QO, e1w_p);
    k_pack<<<dim3(32, 1), 256, 0, stream>>>(e2_w, EV1, 0, EV2, EV1, e2w_p);

    // sort + pack seq; xgT = (w_ih @ seq^T) + bsum written DIRECTLY in [n][j][b]
    // layout via cmode=1 epilogue (A = w_ih rows j, B = seq rows token)
    k_sort<<<32, 256, 0, stream>>>(x, seq);
    k_pack<<<dim3(8, 8), 256, 0, stream>>>(seq, EE, 0, 1024, EE, seq_p);
    k_gemm_t<2, 2><<<8 * 8 * 6, 256, 0, stream>>>(wih_p, 8, seq_p, bsum, nullptr,
                                                  xgT, nullptr, 0, 6016, EE, 1024, 0, 1);

    // LSTM: 32 fused steps, double-buffered h planes (kernel-boundary coherence)
    for (int nstep = 0; nstep < NN; nstep++) {
        const short* hr = hbuf + (size_t)(nstep & 1) * HSZ;
        short* hw = hbuf + (size_t)((nstep + 1) & 1) * HSZ;
        k_lstm_step<<<LBLK, 256, 0, stream>>>(wf, hr, hw,
                                              xgT + (size_t)nstep * (G4 * BB), ct, ht);
    }

    // evaluator plan-side bias (includes e1_b)
    k_pb<<<dim3(4, BB), 256, 0, stream>>>(ht, e1at, e1_b, pb);

    // pair MLP (packed pipeline; pairs_p overwrites dead wf — after LSTM)
    k_pairs<<<7936, 256, 0, stream>>>(x, iijj, pairs_p);
    k_gemm_t<2, 1><<<8 * 5 * 16, 256, 0, stream>>>(pairs_p, 16, q1w_p, q1beff, nullptr,
                                                   nullptr, q1out_p, 20, ROWS, QIN, Q1O, 1, 0);
    k_gemm_t<1, 1><<<8 * 3 * 16, 256, 0, stream>>>(q1out_p, 20, q2w_p, q2_b, nullptr,
                                                   nullptr, q2out_p, 12, ROWS, Q1O, QO, 1, 0);
    k_gemm_t<1, 1><<<8 * 8 * 16, 256, 0, stream>>>(q2out_p, 12, e1w_p, nullptr, pb,
                                                   nullptr, e1out_p, 32, ROWS, QO, EV1, 1, 0);
    k_gemm_t<1, 1><<<8 * 1 * 16, 256, 0, stream>>>(e1out_p, 32, e2w_p, e2_b, nullptr,
                                                   e2out, nullptr, 0, ROWS, EV1, EV2, 1, 0);
    k_e34<<<62, 256, 0, stream>>>(e2out, e3t, e3_b, e4_w, e4_b, out);
}

// Round 9
// 871.940 us; speedup vs baseline: 1.0274x; 1.0274x over previous
//
#include <hip/hip_runtime.h>
#include <math.h>

// Problem dims
#define BB 32
#define NN 32
#define EE 256
#define HH 1500
#define G4 6000      // 4*HH
#define QIN 512
#define Q1O 600
#define QO 300
#define EV1 1000
#define EV2 100
#define EV3 10
#define PP 496       // N*(N-1)/2
#define ROWS (BB*PP) // 15872
#define BH (BB*HH)   // 48000

// Packed GEMM operand tile: [planes][128 rows][40 shorts]; plane = 5120 shorts
#define TROW 40
#define TPLANE (128 * TROW)   // 5120 shorts per plane

// LSTM fused geometry: 375 blocks x 4 h-indices, K padded to 47*32=1504
#define LKT 47
#define LBLK 375
#define LTILE 2048            // h-buffer shorts per kt: [2 planes][32 rows][32 k]
#define HSZ (LKT * LTILE)     // 96256 shorts per h buffer
#define LTILE_W 512           // wf shorts per (blk,kt): [16 rows][32 k] single plane
#define HSZW (LKT * LTILE_W)  // 24064 shorts per block slice

typedef __attribute__((ext_vector_type(8))) short bf16x8;
typedef __attribute__((ext_vector_type(4))) float f32x4;

__device__ __forceinline__ float sigm(float x) { return 1.f / (1.f + expf(-x)); }

// RNE round to bf16, kept as fp32 bit pattern (low 16 bits zero)
__device__ __forceinline__ unsigned bf16h(float x) {
    unsigned u = __float_as_uint(x);
    return (u + 0x7FFFu + ((u >> 16) & 1u)) & 0xFFFF0000u;
}

// split float4 -> hi/lo bf16 quads, 8B store each
__device__ __forceinline__ void split4(float4 v, short* hp, short* lp) {
    unsigned h0 = bf16h(v.x), h1 = bf16h(v.y), h2 = bf16h(v.z), h3 = bf16h(v.w);
    float r0 = v.x - __uint_as_float(h0);
    float r1 = v.y - __uint_as_float(h1);
    float r2 = v.z - __uint_as_float(h2);
    float r3 = v.w - __uint_as_float(h3);
    unsigned l0 = bf16h(r0), l1 = bf16h(r1), l2 = bf16h(r2), l3 = bf16h(r3);
    uint2 hw, lw;
    hw.x = (h0 >> 16) | (h1 & 0xFFFF0000u);
    hw.y = (h2 >> 16) | (h3 & 0xFFFF0000u);
    lw.x = (l0 >> 16) | (l1 & 0xFFFF0000u);
    lw.y = (l2 >> 16) | (l3 & 0xFFFF0000u);
    *(uint2*)hp = hw;
    *(uint2*)lp = lw;
}

// hi-plane only version (pure bf16)
__device__ __forceinline__ void hi4(float4 v, short* hp) {
    unsigned h0 = bf16h(v.x), h1 = bf16h(v.y), h2 = bf16h(v.z), h3 = bf16h(v.w);
    uint2 hw;
    hw.x = (h0 >> 16) | (h1 & 0xFFFF0000u);
    hw.y = (h2 >> 16) | (h3 & 0xFFFF0000u);
    *(uint2*)hp = hw;
}

// async 16B global -> LDS (dest wave-uniform; HW adds lane*16B)
#define ASYNC16(dst, src) \
    __builtin_amdgcn_global_load_lds((const __attribute__((address_space(1))) unsigned*)(src), \
                                     (__attribute__((address_space(3))) unsigned*)(dst), 16, 0, 0)

// ---------------- init helpers ----------------
__global__ void k_zero(float* a, int n) {
    int i = blockIdx.x * 256 + threadIdx.x;
    if (i < n) a[i] = 0.f;
}

__global__ void k_iijj(int* iijj) {
    int p = threadIdx.x;
    if (p >= PP) return;
    int i = 0, p0 = 0;
    while (p >= p0 + (NN - 1 - i)) { p0 += NN - 1 - i; i++; }
    iijj[p] = i;
    iijj[PP + p] = i + 1 + (p - p0);
}

// q1 effective bias: q1_b[o] + sum over odd k of q1_w[o][k]  (PE at pos 0)
__global__ void k_q1beff(const float* q1w, const float* q1b, float* beff) {
    int o = blockIdx.x * 256 + threadIdx.x;
    if (o >= Q1O) return;
    float a = q1b[o];
    for (int k = 1; k < QIN; k += 2) a += q1w[o * QIN + k];
    beff[o] = a;
}

__global__ void k_addb(const float* a, const float* b, float* c, int n) {
    int i = blockIdx.x * 256 + threadIdx.x;
    if (i < n) c[i] = a[i] + b[i];
}

// ---------------- transpose (sub-range of columns) ----------------
__global__ void k_transpose(const float* __restrict__ src, float* __restrict__ dst,
                            int R, int C, int c0, int csub) {
    __shared__ float tile[32][33];
    int cb = blockIdx.x * 32, rb = blockIdx.y * 32;
    for (int dy = threadIdx.y; dy < 32; dy += 8) {
        int r = rb + dy, c = cb + threadIdx.x;
        if (r < R && c < csub) tile[dy][threadIdx.x] = src[(size_t)r * C + c0 + c];
    }
    __syncthreads();
    for (int dy = threadIdx.y; dy < 32; dy += 8) {
        int c = cb + dy, r = rb + threadIdx.x;
        if (c < csub && r < R) dst[(size_t)c * R + r] = tile[threadIdx.x][dy];
    }
}

// ---------------- pack fp32 [NR x K from col0] -> blocked bf16 hi/lo tiles ----------------
// dst: [mt][kt][2][128][40] shorts. gridDim.x = KT, gridDim.y = ceil(NR/128). Pads zeroed.
__global__ void k_pack(const float* __restrict__ src, int ld, int col0, int NR, int K,
                       short* __restrict__ D) {
    int kt = blockIdx.x, mt = blockIdx.y, KT = gridDim.x;
    size_t tb = ((size_t)mt * KT + kt) * (2 * TPLANE);
    for (int idx = threadIdx.x; idx < 1024; idx += 256) {
        int rowin = idx >> 3, k4 = (idx & 7) << 2;
        int r = mt * 128 + rowin, k = kt * 32 + k4;
        float4 v = {0.f, 0.f, 0.f, 0.f};
        if (r < NR && k < K) v = *(const float4*)(src + (size_t)r * ld + col0 + k);
        size_t o = tb + rowin * TROW + k4;
        split4(v, D + o, D + o + TPLANE);
    }
}

// single-plane (pure bf16) variant: dst [mt][kt][128][40]
__global__ void k_pack1(const float* __restrict__ src, int ld, int col0, int NR, int K,
                        short* __restrict__ D) {
    int kt = blockIdx.x, mt = blockIdx.y, KT = gridDim.x;
    size_t tb = ((size_t)mt * KT + kt) * TPLANE;
    for (int idx = threadIdx.x; idx < 1024; idx += 256) {
        int rowin = idx >> 3, k4 = (idx & 7) << 2;
        int r = mt * 128 + rowin, k = kt * 32 + k4;
        float4 v = {0.f, 0.f, 0.f, 0.f};
        if (r < NR && k < K) v = *(const float4*)(src + (size_t)r * ld + col0 + k);
        hi4(v, D + tb + rowin * TROW + k4);
    }
}

// ---------------- pack w_hh gate-interleaved, PURE bf16, for fused LSTM ----------------
// wf[blk 375][kt 47][16 rows][32 k] shorts. row = h_loc*4 + gate,
// h_glob = blk*4 + h_loc. K pads zero.
__global__ void k_pack_wf(const float* __restrict__ whh, short* __restrict__ wf) {
    int kt = blockIdx.x, blk = blockIdx.y;
    size_t tb = ((size_t)blk * LKT + kt) * LTILE_W;
    int t = threadIdx.x;                  // 128 threads: one float4 each
    int row = t >> 3, k4 = (t & 7) << 2;
    int g = row & 3, h_glob = blk * 4 + (row >> 2);
    int k = kt * 32 + k4;
    float4 v = {0.f, 0.f, 0.f, 0.f};
    if (k < HH) {
        int j = g * HH + h_glob;
        v = *(const float4*)(whh + (size_t)j * HH + k);
    }
    hi4(v, wf + tb + row * 32 + k4);
}

// ---------------- sort along parts axis: bitonic network (static indices) ----------------
__global__ void k_sort(const float* __restrict__ x, float* __restrict__ seq) {
    int tid = blockIdx.x * 256 + threadIdx.x;
    if (tid >= BB * EE) return;
    int b = tid / EE, e = tid % EE;
    float v[NN];
#pragma unroll
    for (int n = 0; n < NN; n++) v[n] = x[(b * NN + n) * EE + e];
#pragma unroll
    for (int kk = 2; kk <= NN; kk <<= 1) {
#pragma unroll
        for (int jj = kk >> 1; jj > 0; jj >>= 1) {
#pragma unroll
            for (int i = 0; i < NN; i++) {
                int l = i ^ jj;
                if (l > i) {
                    bool up = (i & kk) == 0;
                    float a = v[i], c = v[l];
                    bool sw = up ? (a > c) : (a < c);
                    float lo = sw ? c : a, hi = sw ? a : c;
                    v[i] = lo; v[l] = hi;
                }
            }
        }
    }
#pragma unroll
    for (int n = 0; n < NN; n++) seq[(n * BB + b) * EE + e] = v[n];
}

// ---------------- pairs gather, writes single-plane bf16 tiles directly ----------------
__global__ void k_pairs(const float* __restrict__ x, const int* __restrict__ iijj,
                        short* __restrict__ P) {
    int idx = blockIdx.x * 256 + threadIdx.x; // quad index
    int r = idx >> 7;
    if (r >= ROWS) return;
    int q = idx & 127, k = q << 2;
    int b = r / PP, p = r - b * PP;
    int part = (k < EE) ? iijj[p] : iijj[PP + p];
    float4 v = *(const float4*)(x + (size_t)(b * NN + part) * EE + (k & (EE - 1)));
    int mt = r >> 7, rowin = r & 127, kt = k >> 5, k4 = k & 31;
    size_t o = ((size_t)mt * 16 + kt) * TPLANE + rowin * TROW + k4;
    hi4(v, P + o);
}

// ---------------- templated MFMA GEMM ----------------
// APL/BPL: operand planes (2 = hi/lo bf16x3 style, 1 = pure bf16).
// MFMAs per k-step = APL + BPL - 1 (ah*bh [+ ah*bl] [+ al*bh]).
// PPL: pack-out planes. XCD-grouped 1D grid: grid = 8 * NT * ceil(MT/8).
// cmode 0: C[row][col] = act(acc + bias[col] + pbm). cmode 1: transposed xgT write,
// xgT[(col>>5)*G4*32 + row*32 + (col&31)] = acc + bias[row], guarded row < G4.
// Pack-out written unguarded (cols >= N compute exact 0 from zero-padded B).
template<int APL, int BPL, int PPL>
__global__ __launch_bounds__(256, 2)
void k_gemm_t(const short* __restrict__ Ap, int AKT, const short* __restrict__ Bp,
              const float* __restrict__ bias, const float* __restrict__ pbm,
              float* __restrict__ Cf32, short* __restrict__ P, int PKT,
              int M, int K, int N, int relu, int cmode) {
    const int ATS = APL * TPLANE;          // A tile shorts
    const int BTS = BPL * TPLANE;          // B tile shorts
    __shared__ __align__(16) short lds[2][(APL + BPL) * TPLANE];

    int MT = M >> 7, NT = (N + 127) >> 7;
    int bid = blockIdx.x;
    int xcd = bid & 7, rr = bid >> 3;
    int nt = rr % NT, mtc = rr / NT;
    int mt = mtc * 8 + xcd;
    if (mt >= MT) return;

    int tid = threadIdx.x;
    int lane = tid & 63, w = tid >> 6;
    int wr = w >> 1, wc = w & 1;
    int ksteps = (K + 31) >> 5;

    const short* gA = Ap + (size_t)mt * AKT * ATS;
    const short* gB = Bp + (size_t)nt * ksteps * BTS;

#define STAGE(bufi, kt) do { \
        const short* sa_ = gA + (size_t)(kt) * ATS + lane * 8; \
        const short* sb_ = gB + (size_t)(kt) * BTS + lane * 8; \
        for (int c_ = w; c_ < ATS / 512; c_ += 4) \
            ASYNC16(&lds[bufi][c_ * 512], sa_ + c_ * 512); \
        for (int c_ = w; c_ < BTS / 512; c_ += 4) \
            ASYNC16(&lds[bufi][ATS + c_ * 512], sb_ + c_ * 512); \
    } while (0)

    f32x4 acc[4][4];
#pragma unroll
    for (int mi = 0; mi < 4; mi++)
#pragma unroll
        for (int ni = 0; ni < 4; ni++) acc[mi][ni] = (f32x4){0.f, 0.f, 0.f, 0.f};

    int l15 = lane & 15;
    int kc8 = (lane >> 4) << 3;

    STAGE(0, 0);
    __syncthreads();

    int buf = 0;
    for (int kt = 0; kt < ksteps; kt++) {
        if (kt + 1 < ksteps) STAGE(buf ^ 1, kt + 1);

        const short* LA = &lds[buf][0];
        const short* LB = &lds[buf][ATS];

        bf16x8 ah[4], al[4];
#pragma unroll
        for (int mi = 0; mi < 4; mi++) {
            int o = (wr * 64 + mi * 16 + l15) * TROW + kc8;
            ah[mi] = *(const bf16x8*)(LA + o);
            if constexpr (APL == 2) al[mi] = *(const bf16x8*)(LA + TPLANE + o);
        }
#pragma unroll
        for (int ni = 0; ni < 4; ni++) {
            int o = (wc * 64 + ni * 16 + l15) * TROW + kc8;
            bf16x8 bh = *(const bf16x8*)(LB + o);
            bf16x8 bl;
            if constexpr (BPL == 2) bl = *(const bf16x8*)(LB + TPLANE + o);
#pragma unroll
            for (int mi = 0; mi < 4; mi++) {
                acc[mi][ni] = __builtin_amdgcn_mfma_f32_16x16x32_bf16(ah[mi], bh, acc[mi][ni], 0, 0, 0);
                if constexpr (BPL == 2)
                    acc[mi][ni] = __builtin_amdgcn_mfma_f32_16x16x32_bf16(ah[mi], bl, acc[mi][ni], 0, 0, 0);
                if constexpr (APL == 2)
                    acc[mi][ni] = __builtin_amdgcn_mfma_f32_16x16x32_bf16(al[mi], bh, acc[mi][ni], 0, 0, 0);
            }
        }
        __syncthreads();
        buf ^= 1;
    }
#undef STAGE

    const int PTS = PPL * TPLANE;
#pragma unroll
    for (int ni = 0; ni < 4; ni++) {
        int col = nt * 128 + wc * 64 + ni * 16 + l15;
        float bb = (cmode == 0 && bias && col < N) ? bias[col] : 0.f;
#pragma unroll
        for (int mi = 0; mi < 4; mi++) {
            int rbase = mt * 128 + wr * 64 + mi * 16 + ((lane >> 4) << 2);
#pragma unroll
            for (int r4 = 0; r4 < 4; r4++) {
                int row = rbase + r4;
                float v = acc[mi][ni][r4];
                if (cmode == 1) {
                    if (row < G4)
                        Cf32[(size_t)(col >> 5) * (G4 * BB) + (size_t)row * BB + (col & 31)]
                            = v + bias[row];
                    continue;
                }
                v += bb;
                if (pbm && col < N) v += pbm[(size_t)(row / PP) * N + col];
                if (relu) v = fmaxf(v, 0.f);
                if (Cf32 && col < N) Cf32[(size_t)row * N + col] = v;
                if (P) {
                    unsigned h = bf16h(v);
                    int kt2 = col >> 5, kin = col & 31, rowin = row & 127, mtt = row >> 7;
                    size_t o = ((size_t)mtt * PKT + kt2) * PTS + rowin * TROW + kin;
                    P[o] = (short)(h >> 16);
                    if constexpr (PPL == 2) {
                        unsigned l = bf16h(v - __uint_as_float(h));
                        P[o + TPLANE] = (short)(l >> 16);
                    }
                }
            }
        }
    }
}

// ---------------- fused LSTM step: 375 blocks x 8 waves, k-split 4-way ----------------
// Block owns h [blk*4, blk*4+4). wave = (ks, mi): ks quarters the kt range (dependent
// chain 47 -> 12), LDS-reduce ks>0 partials into ks=0; mi = batch half.
// acc init = xgT preactivation. h in hi/lo bf16 planes; weights PURE bf16
// (18 MB, per-XCD slice L2-resident across steps). 4-lane shuffle gathers gates.
__global__ __launch_bounds__(512, 1)
void k_lstm_step(const short* __restrict__ wf, const short* __restrict__ hbuf_r,
                 short* __restrict__ hbuf_w, const float* __restrict__ xgT_n,
                 float* __restrict__ ct, float* __restrict__ ht) {
    __shared__ f32x4 red[3][2][64];
    int tid = threadIdx.x, lane = tid & 63, wave = tid >> 6;
    int ks = wave >> 1, mi = wave & 1;
    int blk = blockIdx.x;
    int l15 = lane & 15, bg = lane >> 4;
    int kc8 = bg << 3;
    int n = l15, g = n & 3;
    int h_glob = blk * 4 + (n >> 2);
    int kt0 = ks * 12, ktend = (ks == 3) ? LKT : (kt0 + 12);

    f32x4 accA = {0.f, 0.f, 0.f, 0.f}, accB = {0.f, 0.f, 0.f, 0.f};
    if (ks == 0)
        accA = *(const f32x4*)(xgT_n + (size_t)(g * HH + h_glob) * BB + mi * 16 + bg * 4);

    const short* wp0 = wf + (size_t)blk * HSZW + l15 * 32 + kc8;
    const short* hp0 = hbuf_r + (mi * 16 + l15) * 32 + kc8;

    // depth-3 software pipeline, named-register rotation
    bf16x8 a0h = *(const bf16x8*)(hp0 + (size_t)kt0 * LTILE);
    bf16x8 a0l = *(const bf16x8*)(hp0 + (size_t)kt0 * LTILE + 1024);
    bf16x8 b0  = *(const bf16x8*)(wp0 + (size_t)kt0 * LTILE_W);
    bf16x8 a1h = *(const bf16x8*)(hp0 + (size_t)(kt0 + 1) * LTILE);
    bf16x8 a1l = *(const bf16x8*)(hp0 + (size_t)(kt0 + 1) * LTILE + 1024);
    bf16x8 b1  = *(const bf16x8*)(wp0 + (size_t)(kt0 + 1) * LTILE_W);
    bf16x8 a2h = *(const bf16x8*)(hp0 + (size_t)(kt0 + 2) * LTILE);
    bf16x8 a2l = *(const bf16x8*)(hp0 + (size_t)(kt0 + 2) * LTILE + 1024);
    bf16x8 b2  = *(const bf16x8*)(wp0 + (size_t)(kt0 + 2) * LTILE_W);
    for (int kt = kt0; kt < ktend; kt++) {
        bf16x8 a3h, a3l, b3;
        if (kt + 3 < ktend) {
            const short* hp = hp0 + (size_t)(kt + 3) * LTILE;
            const short* wp = wp0 + (size_t)(kt + 3) * LTILE_W;
            a3h = *(const bf16x8*)(hp);
            a3l = *(const bf16x8*)(hp + 1024);
            b3  = *(const bf16x8*)(wp);
        }
        accA = __builtin_amdgcn_mfma_f32_16x16x32_bf16(a0h, b0, accA, 0, 0, 0);
        accB = __builtin_amdgcn_mfma_f32_16x16x32_bf16(a0l, b0, accB, 0, 0, 0);
        a0h = a1h; a0l = a1l; b0 = b1;
        a1h = a2h; a1l = a2l; b1 = b2;
        a2h = a3h; a2l = a3l; b2 = b3;
    }
    f32x4 acc = accA + accB;

    // reduce ks>0 partials into ks=0 waves
    if (ks > 0) red[ks - 1][mi][lane] = acc;
    __syncthreads();
    if (ks > 0) return;
    acc += red[0][mi][lane] + red[1][mi][lane] + red[2][mi][lane];

    // gather the 4 gates across the 4-lane group (lane n, n^1, n^2, n^3)
    float gg[4][4];
#pragma unroll
    for (int r = 0; r < 4; r++) {
        float a = acc[r];
        gg[0][r] = a;
        gg[1][r] = __shfl_xor(a, 1);
        gg[2][r] = __shfl_xor(a, 2);
        gg[3][r] = __shfl_xor(a, 3);
    }

    if ((n & 3) == 0) {
        int kth = h_glob >> 5, kin = h_glob & 31;
#pragma unroll
        for (int r = 0; r < 4; r++) {
            int b = mi * 16 + bg * 4 + r;
            float ci = ct[h_glob * BB + b];
            float cn = sigm(gg[1][r]) * ci + sigm(gg[0][r]) * tanhf(gg[2][r]);
            ct[h_glob * BB + b] = cn;
            float hv = sigm(gg[3][r]) * tanhf(cn);
            ht[h_glob * BB + b] = hv;
            unsigned hh = bf16h(hv);
            unsigned hl = bf16h(hv - __uint_as_float(hh));
            size_t o = (size_t)kth * LTILE + b * 32 + kin;
            hbuf_w[o] = (short)(hh >> 16);
            hbuf_w[o + 1024] = (short)(hl >> 16);
        }
    }
}

// ---------------- plan-side e1 bias (plan in ht layout [h][b]) ----------------
__global__ void k_pb(const float* __restrict__ ht, const float* __restrict__ e1at,
                     const float* __restrict__ e1b, float* __restrict__ pb) {
    __shared__ float ps[HH];
    int b = blockIdx.y;
    for (int idx = threadIdx.x; idx < HH; idx += 256) ps[idx] = ht[(size_t)idx * BB + b];
    __syncthreads();
    int o = blockIdx.x * 256 + threadIdx.x;
    if (o >= EV1) return;
    float acc = e1b[o];
    for (int k = 0; k < HH; k++) acc += ps[k] * e1at[(size_t)k * EV1 + o];
    pb[b * EV1 + o] = acc;
}

// ---------------- fused e3 + e4 tail ----------------
__global__ void k_e34(const float* __restrict__ e2out, const float* __restrict__ e3t,
                      const float* __restrict__ e3b, const float* __restrict__ e4w,
                      const float* __restrict__ e4b, float* __restrict__ out) {
    __shared__ float wt[EV2 * EV3];
    for (int idx = threadIdx.x; idx < EV2 * EV3; idx += 256) wt[idx] = e3t[idx];
    __syncthreads();
    int r = blockIdx.x * 256 + threadIdx.x;
    if (r >= ROWS) return;
    float h3[EV3];
#pragma unroll
    for (int o3 = 0; o3 < EV3; o3++) h3[o3] = e3b[o3];
    for (int k = 0; k < EV2; k++) {
        float v = e2out[(size_t)r * EV2 + k];
#pragma unroll
        for (int o3 = 0; o3 < EV3; o3++) h3[o3] += v * wt[k * EV3 + o3];
    }
    float acc = e4b[0];
#pragma unroll
    for (int o3 = 0; o3 < EV3; o3++) acc += fmaxf(h3[o3], 0.f) * e4w[o3];
    out[r] = fmaxf(acc, 0.f);
}

// ---------------- host launch ----------------
extern "C" void kernel_launch(void* const* d_in, const int* in_sizes, int n_in,
                              void* d_out, int out_size, void* d_ws, size_t ws_size,
                              hipStream_t stream) {
    const float* x    = (const float*)d_in[0];
    const float* w_ih = (const float*)d_in[1];
    const float* w_hh = (const float*)d_in[2];
    const float* b_ih = (const float*)d_in[3];
    const float* b_hh = (const float*)d_in[4];
    const float* q1_w = (const float*)d_in[5];
    const float* q1_b = (const float*)d_in[6];
    const float* q2_w = (const float*)d_in[7];
    const float* q2_b = (const float*)d_in[8];
    const float* e1_w = (const float*)d_in[9];
    const float* e1_b = (const float*)d_in[10];
    const float* e2_w = (const float*)d_in[11];
    const float* e2_b = (const float*)d_in[12];
    const float* e3_w = (const float*)d_in[13];
    const float* e3_b = (const float*)d_in[14];
    const float* e4_w = (const float*)d_in[15];
    const float* e4_b = (const float*)d_in[16];
    float* out = (float*)d_out;
    float* ws = (float*)d_ws;

    // ---- workspace layout (float offsets) ----
    // regionA (23M floats), phase-aliased:
    //  pack/xg : wf [0,4.52M) | seq_p [4.6M,4.93M) | wih_p [5.0M,6.93M)
    //  LSTM    : wf [0,4.52M)
    //  q1      : pairs_p [0,5.08M) | q1out_p [10.2M,16.55M)   (wf/seq_p/wih_p dead)
    //  e1      : e1out_p [0,10.16M)  (pairs_p dead; q1out_p dead after q2)
    //  e2      : e1out_p | e2out [20.4M,21.99M)
    size_t off = 0;
    float* seq    = ws + off; off += (size_t)NN * BB * EE;   // 262,144
    size_t regionA = off; off += 23000000;
    short* wf       = (short*)(ws + regionA);                // 375*47*512 = 9,024,000 sh
    short* seq_p    = (short*)(ws + regionA + 4600000);      // 655,360 sh
    short* wih_p    = (short*)(ws + regionA + 5000000);      // 3,850,240 sh
    short* pairs_p  = (short*)(ws + regionA);                // 10,158,080 sh (bf16)
    short* q1out_p  = (short*)(ws + regionA + 10200000);     // 12,697,600 sh (bf16)
    short* e1out_p  = (short*)(ws + regionA);                // 20,316,160 sh (bf16)
    float* e2out    = ws + regionA + 20400000;               // 1,587,200 fl
    float* xgT    = ws + off; off += 7618560;                // 6,144,000 fl; q2out_p alias
    short* q2out_p  = (short*)xgT;                           // 7,618,560 sh (bf16)
    float* ht     = ws + off; off += BH;
    float* ct     = ws + off; off += BH;
    short* hbuf   = (short*)(ws + off); off += 96256;        // 2 x HSZ shorts
    short* q1w_p  = (short*)(ws + off); off += 409600;       // single-plane (half used)
    short* q2w_p  = (short*)(ws + off); off += 291840;
    short* e1w_p  = (short*)(ws + off); off += 409600;
    short* e2w_p  = (short*)(ws + off); off += 163840;
    float* e1at   = ws + off; off += (size_t)HH * EV1;
    float* e3t    = ws + off; off += 1024;
    float* pb     = ws + off; off += BB * EV1;
    float* q1beff = ws + off; off += 1024;
    float* bsum   = ws + off; off += 6016;
    int*   iijj   = (int*)(ws + off); off += 1024;

    dim3 tb(32, 8);

    // init
    k_iijj<<<1, 512, 0, stream>>>(iijj);
    k_q1beff<<<3, 256, 0, stream>>>(q1_w, q1_b, q1beff);
    k_addb<<<24, 256, 0, stream>>>(b_ih, b_hh, bsum, G4);
    k_zero<<<188, 256, 0, stream>>>(ct, BH);
    k_zero<<<376, 256, 0, stream>>>((float*)hbuf, 96256);

    // weight transforms
    k_pack_wf<<<dim3(LKT, LBLK), 128, 0, stream>>>(w_hh, wf);
    k_transpose<<<dim3(47, 32), tb, 0, stream>>>(e1_w, e1at, EV1, HH + QO, 0, HH);
    k_transpose<<<dim3(4, 1), tb, 0, stream>>>(e3_w, e3t, EV3, EV2, 0, EV2);
    k_pack<<<dim3(8, 47), 256, 0, stream>>>(w_ih, EE, 0, G4, EE, wih_p);
    k_pack1<<<dim3(16, 5), 256, 0, stream>>>(q1_w, QIN, 0, Q1O, QIN, q1w_p);
    k_pack<<<dim3(19, 3), 256, 0, stream>>>(q2_w, Q1O, 0, QO, Q1O, q2w_p);
    k_pack<<<dim3(10, 8), 256, 0, stream>>>(e1_w, HH + QO, HH, EV1, QO, e1w_p);
    k_pack<<<dim3(32, 1), 256, 0, stream>>>(e2_w, EV1, 0, EV2, EV1, e2w_p);

    // sort + pack seq; xgT = (w_ih @ seq^T) + bsum written DIRECTLY in [n][j][b]
    // layout via cmode=1 epilogue (full hi/lo x hi/lo: feeds the 32-step recurrence)
    k_sort<<<32, 256, 0, stream>>>(x, seq);
    k_pack<<<dim3(8, 8), 256, 0, stream>>>(seq, EE, 0, 1024, EE, seq_p);
    k_gemm_t<2, 2, 1><<<8 * 8 * 6, 256, 0, stream>>>(wih_p, 8, seq_p, bsum, nullptr,
                                                     xgT, nullptr, 0, 6016, EE, 1024, 0, 1);

    // LSTM: 32 fused steps, double-buffered h planes (kernel-boundary coherence)
    for (int nstep = 0; nstep < NN; nstep++) {
        const short* hr = hbuf + (size_t)(nstep & 1) * HSZ;
        short* hw = hbuf + (size_t)((nstep + 1) & 1) * HSZ;
        k_lstm_step<<<LBLK, 512, 0, stream>>>(wf, hr, hw,
                                              xgT + (size_t)nstep * (G4 * BB), ct, ht);
    }

    // evaluator plan-side bias (includes e1_b)
    k_pb<<<dim3(4, BB), 256, 0, stream>>>(ht, e1at, e1_b, pb);

    // pair MLP (packed pipeline; pairs_p overwrites dead wf — after LSTM)
    k_pairs<<<7936, 256, 0, stream>>>(x, iijj, pairs_p);
    k_gemm_t<1, 1, 1><<<8 * 5 * 16, 256, 0, stream>>>(pairs_p, 16, q1w_p, q1beff, nullptr,
                                                      nullptr, q1out_p, 20, ROWS, QIN, Q1O, 1, 0);
    k_gemm_t<1, 2, 1><<<8 * 3 * 16, 256, 0, stream>>>(q1out_p, 20, q2w_p, q2_b, nullptr,
                                                      nullptr, q2out_p, 12, ROWS, Q1O, QO, 1, 0);
    k_gemm_t<1, 2, 1><<<8 * 8 * 16, 256, 0, stream>>>(q2out_p, 12, e1w_p, nullptr, pb,
                                                      nullptr, e1out_p, 32, ROWS, QO, EV1, 1, 0);
    k_gemm_t<1, 2, 1><<<8 * 1 * 16, 256, 0, stream>>>(e1out_p, 32, e2w_p, e2_b, nullptr,
                                                      e2out, nullptr, 0, ROWS, EV1, EV2, 1, 0);
    k_e34<<<62, 256, 0, stream>>>(e2out, e3t, e3_b, e4_w, e4_b, out);
}

// Round 10
// 841.722 us; speedup vs baseline: 1.0643x; 1.0359x over previous
//
#include <hip/hip_runtime.h>
#include <math.h>

// Problem dims
#define BB 32
#define NN 32
#define EE 256
#define HH 1500
#define G4 6000      // 4*HH
#define QIN 512
#define Q1O 600
#define QO 300
#define EV1 1000
#define EV2 100
#define EV3 10
#define PP 496       // N*(N-1)/2
#define ROWS (BB*PP) // 15872
#define BH (BB*HH)   // 48000

// Packed GEMM operand tile: [planes][128 rows][40 shorts]; plane = 5120 shorts
#define TROW 40
#define TPLANE (128 * TROW)   // 5120 shorts per plane

// LSTM fused geometry: 375 blocks x 4 h-indices, K padded to 47*32=1504
#define LKT 47
#define LBLK 375
#define LTILE 2048            // h-buffer shorts per kt: [2 planes][32 rows][32 k]
#define HSZ (LKT * LTILE)     // 96256 shorts per h buffer
#define LTILE_W 512           // wf shorts per (blk,kt): [16 rows][32 k] single plane
#define HSZW (LKT * LTILE_W)  // 24064 shorts per block slice

typedef __attribute__((ext_vector_type(8))) short bf16x8;
typedef __attribute__((ext_vector_type(4))) float f32x4;

__device__ __forceinline__ float sigm(float x) { return 1.f / (1.f + expf(-x)); }

// RNE round to bf16, kept as fp32 bit pattern (low 16 bits zero)
__device__ __forceinline__ unsigned bf16h(float x) {
    unsigned u = __float_as_uint(x);
    return (u + 0x7FFFu + ((u >> 16) & 1u)) & 0xFFFF0000u;
}

// split float4 -> hi/lo bf16 quads, 8B store each
__device__ __forceinline__ void split4(float4 v, short* hp, short* lp) {
    unsigned h0 = bf16h(v.x), h1 = bf16h(v.y), h2 = bf16h(v.z), h3 = bf16h(v.w);
    float r0 = v.x - __uint_as_float(h0);
    float r1 = v.y - __uint_as_float(h1);
    float r2 = v.z - __uint_as_float(h2);
    float r3 = v.w - __uint_as_float(h3);
    unsigned l0 = bf16h(r0), l1 = bf16h(r1), l2 = bf16h(r2), l3 = bf16h(r3);
    uint2 hw, lw;
    hw.x = (h0 >> 16) | (h1 & 0xFFFF0000u);
    hw.y = (h2 >> 16) | (h3 & 0xFFFF0000u);
    lw.x = (l0 >> 16) | (l1 & 0xFFFF0000u);
    lw.y = (l2 >> 16) | (l3 & 0xFFFF0000u);
    *(uint2*)hp = hw;
    *(uint2*)lp = lw;
}

// hi-plane only version (pure bf16)
__device__ __forceinline__ void hi4(float4 v, short* hp) {
    unsigned h0 = bf16h(v.x), h1 = bf16h(v.y), h2 = bf16h(v.z), h3 = bf16h(v.w);
    uint2 hw;
    hw.x = (h0 >> 16) | (h1 & 0xFFFF0000u);
    hw.y = (h2 >> 16) | (h3 & 0xFFFF0000u);
    *(uint2*)hp = hw;
}

// async 16B global -> LDS (dest wave-uniform; HW adds lane*16B)
#define ASYNC16(dst, src) \
    __builtin_amdgcn_global_load_lds((const __attribute__((address_space(1))) unsigned*)(src), \
                                     (__attribute__((address_space(3))) unsigned*)(dst), 16, 0, 0)

// ---------------- init helpers ----------------
__global__ void k_zero(float* a, int n) {
    int i = blockIdx.x * 256 + threadIdx.x;
    if (i < n) a[i] = 0.f;
}

__global__ void k_iijj(int* iijj) {
    int p = threadIdx.x;
    if (p >= PP) return;
    int i = 0, p0 = 0;
    while (p >= p0 + (NN - 1 - i)) { p0 += NN - 1 - i; i++; }
    iijj[p] = i;
    iijj[PP + p] = i + 1 + (p - p0);
}

// q1 effective bias: q1_b[o] + sum over odd k of q1_w[o][k]  (PE at pos 0)
__global__ void k_q1beff(const float* q1w, const float* q1b, float* beff) {
    int o = blockIdx.x * 256 + threadIdx.x;
    if (o >= Q1O) return;
    float a = q1b[o];
    for (int k = 1; k < QIN; k += 2) a += q1w[o * QIN + k];
    beff[o] = a;
}

__global__ void k_addb(const float* a, const float* b, float* c, int n) {
    int i = blockIdx.x * 256 + threadIdx.x;
    if (i < n) c[i] = a[i] + b[i];
}

// ---------------- transpose (sub-range of columns) ----------------
__global__ void k_transpose(const float* __restrict__ src, float* __restrict__ dst,
                            int R, int C, int c0, int csub) {
    __shared__ float tile[32][33];
    int cb = blockIdx.x * 32, rb = blockIdx.y * 32;
    for (int dy = threadIdx.y; dy < 32; dy += 8) {
        int r = rb + dy, c = cb + threadIdx.x;
        if (r < R && c < csub) tile[dy][threadIdx.x] = src[(size_t)r * C + c0 + c];
    }
    __syncthreads();
    for (int dy = threadIdx.y; dy < 32; dy += 8) {
        int c = cb + dy, r = rb + threadIdx.x;
        if (c < csub && r < R) dst[(size_t)c * R + r] = tile[threadIdx.x][dy];
    }
}

// ---------------- pack fp32 [NR x K from col0] -> blocked bf16 hi/lo tiles ----------------
// dst: [mt][kt][2][128][40] shorts. gridDim.x = KT, gridDim.y = ceil(NR/128). Pads zeroed.
__global__ void k_pack(const float* __restrict__ src, int ld, int col0, int NR, int K,
                       short* __restrict__ D) {
    int kt = blockIdx.x, mt = blockIdx.y, KT = gridDim.x;
    size_t tb = ((size_t)mt * KT + kt) * (2 * TPLANE);
    for (int idx = threadIdx.x; idx < 1024; idx += 256) {
        int rowin = idx >> 3, k4 = (idx & 7) << 2;
        int r = mt * 128 + rowin, k = kt * 32 + k4;
        float4 v = {0.f, 0.f, 0.f, 0.f};
        if (r < NR && k < K) v = *(const float4*)(src + (size_t)r * ld + col0 + k);
        size_t o = tb + rowin * TROW + k4;
        split4(v, D + o, D + o + TPLANE);
    }
}

// single-plane (pure bf16) variant: dst [mt][kt][128][40]
__global__ void k_pack1(const float* __restrict__ src, int ld, int col0, int NR, int K,
                        short* __restrict__ D) {
    int kt = blockIdx.x, mt = blockIdx.y, KT = gridDim.x;
    size_t tb = ((size_t)mt * KT + kt) * TPLANE;
    for (int idx = threadIdx.x; idx < 1024; idx += 256) {
        int rowin = idx >> 3, k4 = (idx & 7) << 2;
        int r = mt * 128 + rowin, k = kt * 32 + k4;
        float4 v = {0.f, 0.f, 0.f, 0.f};
        if (r < NR && k < K) v = *(const float4*)(src + (size_t)r * ld + col0 + k);
        hi4(v, D + tb + rowin * TROW + k4);
    }
}

// ---------------- pack w_hh gate-interleaved, PURE bf16, for fused LSTM ----------------
// wf[blk 375][kt 47][16 rows][32 k] shorts. row = h_loc*4 + gate,
// h_glob = blk*4 + h_loc. K pads zero.
__global__ void k_pack_wf(const float* __restrict__ whh, short* __restrict__ wf) {
    int kt = blockIdx.x, blk = blockIdx.y;
    size_t tb = ((size_t)blk * LKT + kt) * LTILE_W;
    int t = threadIdx.x;                  // 128 threads: one float4 each
    int row = t >> 3, k4 = (t & 7) << 2;
    int g = row & 3, h_glob = blk * 4 + (row >> 2);
    int k = kt * 32 + k4;
    float4 v = {0.f, 0.f, 0.f, 0.f};
    if (k < HH) {
        int j = g * HH + h_glob;
        v = *(const float4*)(whh + (size_t)j * HH + k);
    }
    hi4(v, wf + tb + row * 32 + k4);
}

// ---------------- sort along parts axis: bitonic network (static indices) ----------------
__global__ void k_sort(const float* __restrict__ x, float* __restrict__ seq) {
    int tid = blockIdx.x * 256 + threadIdx.x;
    if (tid >= BB * EE) return;
    int b = tid / EE, e = tid % EE;
    float v[NN];
#pragma unroll
    for (int n = 0; n < NN; n++) v[n] = x[(b * NN + n) * EE + e];
#pragma unroll
    for (int kk = 2; kk <= NN; kk <<= 1) {
#pragma unroll
        for (int jj = kk >> 1; jj > 0; jj >>= 1) {
#pragma unroll
            for (int i = 0; i < NN; i++) {
                int l = i ^ jj;
                if (l > i) {
                    bool up = (i & kk) == 0;
                    float a = v[i], c = v[l];
                    bool sw = up ? (a > c) : (a < c);
                    float lo = sw ? c : a, hi = sw ? a : c;
                    v[i] = lo; v[l] = hi;
                }
            }
        }
    }
#pragma unroll
    for (int n = 0; n < NN; n++) seq[(n * BB + b) * EE + e] = v[n];
}

// ---------------- pairs gather, writes single-plane bf16 tiles directly ----------------
__global__ void k_pairs(const float* __restrict__ x, const int* __restrict__ iijj,
                        short* __restrict__ P) {
    int idx = blockIdx.x * 256 + threadIdx.x; // quad index
    int r = idx >> 7;
    if (r >= ROWS) return;
    int q = idx & 127, k = q << 2;
    int b = r / PP, p = r - b * PP;
    int part = (k < EE) ? iijj[p] : iijj[PP + p];
    float4 v = *(const float4*)(x + (size_t)(b * NN + part) * EE + (k & (EE - 1)));
    int mt = r >> 7, rowin = r & 127, kt = k >> 5, k4 = k & 31;
    size_t o = ((size_t)mt * 16 + kt) * TPLANE + rowin * TROW + k4;
    hi4(v, P + o);
}

// ---------------- templated MFMA GEMM ----------------
// APL/BPL: operand planes (2 = hi/lo bf16x3 style, 1 = pure bf16).
// MFMAs per k-step = APL + BPL - 1 (ah*bh [+ ah*bl] [+ al*bh]).
// PPL: pack-out planes. XCD-grouped 1D grid: grid = 8 * NT * ceil(MT/8).
// cmode 0: C[row][col] = act(acc + bias[col] + pbm). cmode 1: transposed xgT write,
// xgT[(col>>5)*G4*32 + row*32 + (col&31)] = acc + bias[row], guarded row < G4.
// Pack-out written unguarded (cols >= N compute exact 0 from zero-padded B).
template<int APL, int BPL, int PPL>
__global__ __launch_bounds__(256, 2)
void k_gemm_t(const short* __restrict__ Ap, int AKT, const short* __restrict__ Bp,
              const float* __restrict__ bias, const float* __restrict__ pbm,
              float* __restrict__ Cf32, short* __restrict__ P, int PKT,
              int M, int K, int N, int relu, int cmode) {
    const int ATS = APL * TPLANE;          // A tile shorts
    const int BTS = BPL * TPLANE;          // B tile shorts
    __shared__ __align__(16) short lds[2][(APL + BPL) * TPLANE];

    int MT = M >> 7, NT = (N + 127) >> 7;
    int bid = blockIdx.x;
    int xcd = bid & 7, rr = bid >> 3;
    int nt = rr % NT, mtc = rr / NT;
    int mt = mtc * 8 + xcd;
    if (mt >= MT) return;

    int tid = threadIdx.x;
    int lane = tid & 63, w = tid >> 6;
    int wr = w >> 1, wc = w & 1;
    int ksteps = (K + 31) >> 5;

    const short* gA = Ap + (size_t)mt * AKT * ATS;
    const short* gB = Bp + (size_t)nt * ksteps * BTS;

#define STAGE(bufi, kt) do { \
        const short* sa_ = gA + (size_t)(kt) * ATS + lane * 8; \
        const short* sb_ = gB + (size_t)(kt) * BTS + lane * 8; \
        for (int c_ = w; c_ < ATS / 512; c_ += 4) \
            ASYNC16(&lds[bufi][c_ * 512], sa_ + c_ * 512); \
        for (int c_ = w; c_ < BTS / 512; c_ += 4) \
            ASYNC16(&lds[bufi][ATS + c_ * 512], sb_ + c_ * 512); \
    } while (0)

    f32x4 acc[4][4];
#pragma unroll
    for (int mi = 0; mi < 4; mi++)
#pragma unroll
        for (int ni = 0; ni < 4; ni++) acc[mi][ni] = (f32x4){0.f, 0.f, 0.f, 0.f};

    int l15 = lane & 15;
    int kc8 = (lane >> 4) << 3;

    STAGE(0, 0);
    __syncthreads();

    int buf = 0;
    for (int kt = 0; kt < ksteps; kt++) {
        if (kt + 1 < ksteps) STAGE(buf ^ 1, kt + 1);

        const short* LA = &lds[buf][0];
        const short* LB = &lds[buf][ATS];

        bf16x8 ah[4], al[4];
#pragma unroll
        for (int mi = 0; mi < 4; mi++) {
            int o = (wr * 64 + mi * 16 + l15) * TROW + kc8;
            ah[mi] = *(const bf16x8*)(LA + o);
            if constexpr (APL == 2) al[mi] = *(const bf16x8*)(LA + TPLANE + o);
        }
#pragma unroll
        for (int ni = 0; ni < 4; ni++) {
            int o = (wc * 64 + ni * 16 + l15) * TROW + kc8;
            bf16x8 bh = *(const bf16x8*)(LB + o);
            bf16x8 bl;
            if constexpr (BPL == 2) bl = *(const bf16x8*)(LB + TPLANE + o);
#pragma unroll
            for (int mi = 0; mi < 4; mi++) {
                acc[mi][ni] = __builtin_amdgcn_mfma_f32_16x16x32_bf16(ah[mi], bh, acc[mi][ni], 0, 0, 0);
                if constexpr (BPL == 2)
                    acc[mi][ni] = __builtin_amdgcn_mfma_f32_16x16x32_bf16(ah[mi], bl, acc[mi][ni], 0, 0, 0);
                if constexpr (APL == 2)
                    acc[mi][ni] = __builtin_amdgcn_mfma_f32_16x16x32_bf16(al[mi], bh, acc[mi][ni], 0, 0, 0);
            }
        }
        __syncthreads();
        buf ^= 1;
    }
#undef STAGE

    const int PTS = PPL * TPLANE;
#pragma unroll
    for (int ni = 0; ni < 4; ni++) {
        int col = nt * 128 + wc * 64 + ni * 16 + l15;
        float bb = (cmode == 0 && bias && col < N) ? bias[col] : 0.f;
#pragma unroll
        for (int mi = 0; mi < 4; mi++) {
            int rbase = mt * 128 + wr * 64 + mi * 16 + ((lane >> 4) << 2);
#pragma unroll
            for (int r4 = 0; r4 < 4; r4++) {
                int row = rbase + r4;
                float v = acc[mi][ni][r4];
                if (cmode == 1) {
                    if (row < G4)
                        Cf32[(size_t)(col >> 5) * (G4 * BB) + (size_t)row * BB + (col & 31)]
                            = v + bias[row];
                    continue;
                }
                v += bb;
                if (pbm && col < N) v += pbm[(size_t)(row / PP) * N + col];
                if (relu) v = fmaxf(v, 0.f);
                if (Cf32 && col < N) Cf32[(size_t)row * N + col] = v;
                if (P) {
                    unsigned h = bf16h(v);
                    int kt2 = col >> 5, kin = col & 31, rowin = row & 127, mtt = row >> 7;
                    size_t o = ((size_t)mtt * PKT + kt2) * PTS + rowin * TROW + kin;
                    P[o] = (short)(h >> 16);
                    if constexpr (PPL == 2) {
                        unsigned l = bf16h(v - __uint_as_float(h));
                        P[o + TPLANE] = (short)(l >> 16);
                    }
                }
            }
        }
    }
}

// ---------------- fused LSTM step: 375 blocks x 8 waves, k-split 4-way ----------------
// Block owns h [blk*4, blk*4+4). wave = (ks, mi): ks quarters the kt range (dependent
// chain 47 -> 12), LDS-reduce ks>0 partials into ks=0; mi = batch half.
// acc init = xgT preactivation. h planes written NON-TEMPORAL (bypass L2: shrinks the
// end-of-kernel dirty-L2 writeback set — the invariant ~15 µs/step cost). fp32 ht
// written only when writeht (last step). Weights PURE bf16, L2-resident.
__global__ __launch_bounds__(512, 1)
void k_lstm_step(const short* __restrict__ wf, const short* __restrict__ hbuf_r,
                 short* __restrict__ hbuf_w, const float* __restrict__ xgT_n,
                 float* __restrict__ ct, float* __restrict__ ht, int writeht) {
    __shared__ f32x4 red[3][2][64];
    int tid = threadIdx.x, lane = tid & 63, wave = tid >> 6;
    int ks = wave >> 1, mi = wave & 1;
    int blk = blockIdx.x;
    int l15 = lane & 15, bg = lane >> 4;
    int kc8 = bg << 3;
    int n = l15, g = n & 3;
    int h_glob = blk * 4 + (n >> 2);
    int kt0 = ks * 12, ktend = (ks == 3) ? LKT : (kt0 + 12);

    f32x4 accA = {0.f, 0.f, 0.f, 0.f}, accB = {0.f, 0.f, 0.f, 0.f};
    if (ks == 0)
        accA = *(const f32x4*)(xgT_n + (size_t)(g * HH + h_glob) * BB + mi * 16 + bg * 4);

    const short* wp0 = wf + (size_t)blk * HSZW + l15 * 32 + kc8;
    const short* hp0 = hbuf_r + (mi * 16 + l15) * 32 + kc8;

    // depth-3 software pipeline, named-register rotation
    bf16x8 a0h = *(const bf16x8*)(hp0 + (size_t)kt0 * LTILE);
    bf16x8 a0l = *(const bf16x8*)(hp0 + (size_t)kt0 * LTILE + 1024);
    bf16x8 b0  = *(const bf16x8*)(wp0 + (size_t)kt0 * LTILE_W);
    bf16x8 a1h = *(const bf16x8*)(hp0 + (size_t)(kt0 + 1) * LTILE);
    bf16x8 a1l = *(const bf16x8*)(hp0 + (size_t)(kt0 + 1) * LTILE + 1024);
    bf16x8 b1  = *(const bf16x8*)(wp0 + (size_t)(kt0 + 1) * LTILE_W);
    bf16x8 a2h = *(const bf16x8*)(hp0 + (size_t)(kt0 + 2) * LTILE);
    bf16x8 a2l = *(const bf16x8*)(hp0 + (size_t)(kt0 + 2) * LTILE + 1024);
    bf16x8 b2  = *(const bf16x8*)(wp0 + (size_t)(kt0 + 2) * LTILE_W);
    for (int kt = kt0; kt < ktend; kt++) {
        bf16x8 a3h, a3l, b3;
        if (kt + 3 < ktend) {
            const short* hp = hp0 + (size_t)(kt + 3) * LTILE;
            const short* wp = wp0 + (size_t)(kt + 3) * LTILE_W;
            a3h = *(const bf16x8*)(hp);
            a3l = *(const bf16x8*)(hp + 1024);
            b3  = *(const bf16x8*)(wp);
        }
        accA = __builtin_amdgcn_mfma_f32_16x16x32_bf16(a0h, b0, accA, 0, 0, 0);
        accB = __builtin_amdgcn_mfma_f32_16x16x32_bf16(a0l, b0, accB, 0, 0, 0);
        a0h = a1h; a0l = a1l; b0 = b1;
        a1h = a2h; a1l = a2l; b1 = b2;
        a2h = a3h; a2l = a3l; b2 = b3;
    }
    f32x4 acc = accA + accB;

    // reduce ks>0 partials into ks=0 waves
    if (ks > 0) red[ks - 1][mi][lane] = acc;
    __syncthreads();
    if (ks > 0) return;
    acc += red[0][mi][lane] + red[1][mi][lane] + red[2][mi][lane];

    // gather the 4 gates across the 4-lane group (lane n, n^1, n^2, n^3)
    float gg[4][4];
#pragma unroll
    for (int r = 0; r < 4; r++) {
        float a = acc[r];
        gg[0][r] = a;
        gg[1][r] = __shfl_xor(a, 1);
        gg[2][r] = __shfl_xor(a, 2);
        gg[3][r] = __shfl_xor(a, 3);
    }

    if ((n & 3) == 0) {
        int kth = h_glob >> 5, kin = h_glob & 31;
#pragma unroll
        for (int r = 0; r < 4; r++) {
            int b = mi * 16 + bg * 4 + r;
            float ci = ct[h_glob * BB + b];
            float cn = sigm(gg[1][r]) * ci + sigm(gg[0][r]) * tanhf(gg[2][r]);
            ct[h_glob * BB + b] = cn;
            float hv = sigm(gg[3][r]) * tanhf(cn);
            if (writeht) ht[h_glob * BB + b] = hv;
            unsigned hh = bf16h(hv);
            unsigned hl = bf16h(hv - __uint_as_float(hh));
            size_t o = (size_t)kth * LTILE + b * 32 + kin;
            __builtin_nontemporal_store((short)(hh >> 16), &hbuf_w[o]);
            __builtin_nontemporal_store((short)(hl >> 16), &hbuf_w[o + 1024]);
        }
    }
}

// ---------------- plan-side e1 bias (plan in ht layout [h][b]) ----------------
__global__ void k_pb(const float* __restrict__ ht, const float* __restrict__ e1at,
                     const float* __restrict__ e1b, float* __restrict__ pb) {
    __shared__ float ps[HH];
    int b = blockIdx.y;
    for (int idx = threadIdx.x; idx < HH; idx += 256) ps[idx] = ht[(size_t)idx * BB + b];
    __syncthreads();
    int o = blockIdx.x * 256 + threadIdx.x;
    if (o >= EV1) return;
    float acc = e1b[o];
    for (int k = 0; k < HH; k++) acc += ps[k] * e1at[(size_t)k * EV1 + o];
    pb[b * EV1 + o] = acc;
}

// ---------------- fused e3 + e4 tail ----------------
__global__ void k_e34(const float* __restrict__ e2out, const float* __restrict__ e3t,
                      const float* __restrict__ e3b, const float* __restrict__ e4w,
                      const float* __restrict__ e4b, float* __restrict__ out) {
    __shared__ float wt[EV2 * EV3];
    for (int idx = threadIdx.x; idx < EV2 * EV3; idx += 256) wt[idx] = e3t[idx];
    __syncthreads();
    int r = blockIdx.x * 256 + threadIdx.x;
    if (r >= ROWS) return;
    float h3[EV3];
#pragma unroll
    for (int o3 = 0; o3 < EV3; o3++) h3[o3] = e3b[o3];
    for (int k = 0; k < EV2; k++) {
        float v = e2out[(size_t)r * EV2 + k];
#pragma unroll
        for (int o3 = 0; o3 < EV3; o3++) h3[o3] += v * wt[k * EV3 + o3];
    }
    float acc = e4b[0];
#pragma unroll
    for (int o3 = 0; o3 < EV3; o3++) acc += fmaxf(h3[o3], 0.f) * e4w[o3];
    out[r] = fmaxf(acc, 0.f);
}

// ---------------- host launch ----------------
extern "C" void kernel_launch(void* const* d_in, const int* in_sizes, int n_in,
                              void* d_out, int out_size, void* d_ws, size_t ws_size,
                              hipStream_t stream) {
    const float* x    = (const float*)d_in[0];
    const float* w_ih = (const float*)d_in[1];
    const float* w_hh = (const float*)d_in[2];
    const float* b_ih = (const float*)d_in[3];
    const float* b_hh = (const float*)d_in[4];
    const float* q1_w = (const float*)d_in[5];
    const float* q1_b = (const float*)d_in[6];
    const float* q2_w = (const float*)d_in[7];
    const float* q2_b = (const float*)d_in[8];
    const float* e1_w = (const float*)d_in[9];
    const float* e1_b = (const float*)d_in[10];
    const float* e2_w = (const float*)d_in[11];
    const float* e2_b = (const float*)d_in[12];
    const float* e3_w = (const float*)d_in[13];
    const float* e3_b = (const float*)d_in[14];
    const float* e4_w = (const float*)d_in[15];
    const float* e4_b = (const float*)d_in[16];
    float* out = (float*)d_out;
    float* ws = (float*)d_ws;

    // ---- workspace layout (float offsets) ----
    // regionA (23M floats), phase-aliased:
    //  pack/xg : wf [0,4.52M) | seq_p [4.6M,4.93M) | wih_p [5.0M,6.93M)
    //  LSTM    : wf [0,4.52M)
    //  q1      : pairs_p [0,5.08M) | q1out_p [10.2M,16.55M)   (wf/seq_p/wih_p dead)
    //  e1      : e1out_p [0,10.16M)  (pairs_p dead; q1out_p dead after q2)
    //  e2      : e1out_p | e2out [20.4M,21.99M)
    size_t off = 0;
    float* seq    = ws + off; off += (size_t)NN * BB * EE;   // 262,144
    size_t regionA = off; off += 23000000;
    short* wf       = (short*)(ws + regionA);                // 375*47*512 = 9,024,000 sh
    short* seq_p    = (short*)(ws + regionA + 4600000);      // 655,360 sh
    short* wih_p    = (short*)(ws + regionA + 5000000);      // 3,850,240 sh
    short* pairs_p  = (short*)(ws + regionA);                // 10,158,080 sh (bf16)
    short* q1out_p  = (short*)(ws + regionA + 10200000);     // 12,697,600 sh (bf16)
    short* e1out_p  = (short*)(ws + regionA);                // 20,316,160 sh (bf16)
    float* e2out    = ws + regionA + 20400000;               // 1,587,200 fl
    float* xgT    = ws + off; off += 7618560;                // 6,144,000 fl; q2out_p alias
    short* q2out_p  = (short*)xgT;                           // 7,618,560 sh (bf16)
    float* ht     = ws + off; off += BH;
    float* ct     = ws + off; off += BH;                     // ct + hbuf contiguous: one zero
    short* hbuf   = (short*)(ws + off); off += 96256;        // 2 x HSZ shorts
    short* q1w_p  = (short*)(ws + off); off += 409600;       // single-plane
    short* q2w_p  = (short*)(ws + off); off += 291840;       // single-plane
    short* e1w_p  = (short*)(ws + off); off += 409600;       // single-plane
    short* e2w_p  = (short*)(ws + off); off += 163840;       // single-plane
    float* e1at   = ws + off; off += (size_t)HH * EV1;
    float* e3t    = ws + off; off += 1024;
    float* pb     = ws + off; off += BB * EV1;
    float* q1beff = ws + off; off += 1024;
    float* bsum   = ws + off; off += 6016;
    int*   iijj   = (int*)(ws + off); off += 1024;

    dim3 tb(32, 8);

    // init (ct and hbuf are contiguous -> single zero launch)
    k_iijj<<<1, 512, 0, stream>>>(iijj);
    k_q1beff<<<3, 256, 0, stream>>>(q1_w, q1_b, q1beff);
    k_addb<<<24, 256, 0, stream>>>(b_ih, b_hh, bsum, G4);
    k_zero<<<564, 256, 0, stream>>>(ct, BH + 96256);

    // weight transforms
    k_pack_wf<<<dim3(LKT, LBLK), 128, 0, stream>>>(w_hh, wf);
    k_transpose<<<dim3(47, 32), tb, 0, stream>>>(e1_w, e1at, EV1, HH + QO, 0, HH);
    k_transpose<<<dim3(4, 1), tb, 0, stream>>>(e3_w, e3t, EV3, EV2, 0, EV2);
    k_pack<<<dim3(8, 47), 256, 0, stream>>>(w_ih, EE, 0, G4, EE, wih_p);
    k_pack1<<<dim3(16, 5), 256, 0, stream>>>(q1_w, QIN, 0, Q1O, QIN, q1w_p);
    k_pack1<<<dim3(19, 3), 256, 0, stream>>>(q2_w, Q1O, 0, QO, Q1O, q2w_p);
    k_pack1<<<dim3(10, 8), 256, 0, stream>>>(e1_w, HH + QO, HH, EV1, QO, e1w_p);
    k_pack1<<<dim3(32, 1), 256, 0, stream>>>(e2_w, EV1, 0, EV2, EV1, e2w_p);

    // sort + pack seq; xgT = (w_ih @ seq^T) + bsum written DIRECTLY in [n][j][b]
    // layout via cmode=1 epilogue (full hi/lo x hi/lo: feeds the 32-step recurrence)
    k_sort<<<32, 256, 0, stream>>>(x, seq);
    k_pack<<<dim3(8, 8), 256, 0, stream>>>(seq, EE, 0, 1024, EE, seq_p);
    k_gemm_t<2, 2, 1><<<8 * 8 * 6, 256, 0, stream>>>(wih_p, 8, seq_p, bsum, nullptr,
                                                     xgT, nullptr, 0, 6016, EE, 1024, 0, 1);

    // LSTM: 32 fused steps, double-buffered h planes (kernel-boundary coherence)
    for (int nstep = 0; nstep < NN; nstep++) {
        const short* hr = hbuf + (size_t)(nstep & 1) * HSZ;
        short* hw = hbuf + (size_t)((nstep + 1) & 1) * HSZ;
        k_lstm_step<<<LBLK, 512, 0, stream>>>(wf, hr, hw,
                                              xgT + (size_t)nstep * (G4 * BB), ct, ht,
                                              nstep == NN - 1);
    }

    // evaluator plan-side bias (includes e1_b)
    k_pb<<<dim3(4, BB), 256, 0, stream>>>(ht, e1at, e1_b, pb);

    // pair MLP (packed pipeline; pairs_p overwrites dead wf — after LSTM)
    k_pairs<<<7936, 256, 0, stream>>>(x, iijj, pairs_p);
    k_gemm_t<1, 1, 1><<<8 * 5 * 16, 256, 0, stream>>>(pairs_p, 16, q1w_p, q1beff, nullptr,
                                                      nullptr, q1out_p, 20, ROWS, QIN, Q1O, 1, 0);
    k_gemm_t<1, 1, 1><<<8 * 3 * 16, 256, 0, stream>>>(q1out_p, 20, q2w_p, q2_b, nullptr,
                                                      nullptr, q2out_p, 12, ROWS, Q1O, QO, 1, 0);
    k_gemm_t<1, 1, 1><<<8 * 8 * 16, 256, 0, stream>>>(q2out_p, 12, e1w_p, nullptr, pb,
                                                      nullptr, e1out_p, 32, ROWS, QO, EV1, 1, 0);
    k_gemm_t<1, 1, 1><<<8 * 1 * 16, 256, 0, stream>>>(e1out_p, 32, e2w_p, e2_b, nullptr,
                                                      e2out, nullptr, 0, ROWS, EV1, EV2, 1, 0);
    k_e34<<<62, 256, 0, stream>>>(e2out, e3t, e3_b, e4_w, e4_b, out);
}

// Round 11
// 766.702 us; speedup vs baseline: 1.1685x; 1.0978x over previous
//
#include <hip/hip_runtime.h>
#include <math.h>

// Problem dims
#define BB 32
#define NN 32
#define EE 256
#define HH 1500
#define G4 6000      // 4*HH
#define QIN 512
#define Q1O 600
#define QO 300
#define EV1 1000
#define EV2 100
#define EV3 10
#define PP 496       // N*(N-1)/2
#define ROWS (BB*PP) // 15872
#define BH (BB*HH)   // 48000

// Packed GEMM operand tile: [planes][128 rows][40 shorts]; plane = 5120 shorts
#define TROW 40
#define TPLANE (128 * TROW)   // 5120 shorts per plane

// LSTM fused geometry: 375 blocks x 4 h-indices, K padded to 47*32=1504
#define LKT 47
#define LBLK 375
#define LTILE 1024            // h-buffer shorts per kt: [32 rows][32 k] SINGLE plane
#define HSZ (LKT * LTILE)     // 48128 shorts per h buffer
#define LTILE_W 512           // wf shorts per (blk,kt): [16 rows][32 k] single plane
#define HSZW (LKT * LTILE_W)  // 24064 shorts per block slice

typedef __attribute__((ext_vector_type(8))) short bf16x8;
typedef __attribute__((ext_vector_type(4))) float f32x4;

__device__ __forceinline__ float sigm(float x) { return 1.f / (1.f + expf(-x)); }

// RNE round to bf16, kept as fp32 bit pattern (low 16 bits zero)
__device__ __forceinline__ unsigned bf16h(float x) {
    unsigned u = __float_as_uint(x);
    return (u + 0x7FFFu + ((u >> 16) & 1u)) & 0xFFFF0000u;
}

// split float4 -> hi/lo bf16 quads, 8B store each
__device__ __forceinline__ void split4(float4 v, short* hp, short* lp) {
    unsigned h0 = bf16h(v.x), h1 = bf16h(v.y), h2 = bf16h(v.z), h3 = bf16h(v.w);
    float r0 = v.x - __uint_as_float(h0);
    float r1 = v.y - __uint_as_float(h1);
    float r2 = v.z - __uint_as_float(h2);
    float r3 = v.w - __uint_as_float(h3);
    unsigned l0 = bf16h(r0), l1 = bf16h(r1), l2 = bf16h(r2), l3 = bf16h(r3);
    uint2 hw, lw;
    hw.x = (h0 >> 16) | (h1 & 0xFFFF0000u);
    hw.y = (h2 >> 16) | (h3 & 0xFFFF0000u);
    lw.x = (l0 >> 16) | (l1 & 0xFFFF0000u);
    lw.y = (l2 >> 16) | (l3 & 0xFFFF0000u);
    *(uint2*)hp = hw;
    *(uint2*)lp = lw;
}

// hi-plane only version (pure bf16)
__device__ __forceinline__ void hi4(float4 v, short* hp) {
    unsigned h0 = bf16h(v.x), h1 = bf16h(v.y), h2 = bf16h(v.z), h3 = bf16h(v.w);
    uint2 hw;
    hw.x = (h0 >> 16) | (h1 & 0xFFFF0000u);
    hw.y = (h2 >> 16) | (h3 & 0xFFFF0000u);
    *(uint2*)hp = hw;
}

// async 16B global -> LDS (dest wave-uniform; HW adds lane*16B)
#define ASYNC16(dst, src) \
    __builtin_amdgcn_global_load_lds((const __attribute__((address_space(1))) unsigned*)(src), \
                                     (__attribute__((address_space(3))) unsigned*)(dst), 16, 0, 0)

// ---------------- init helpers ----------------
__global__ void k_zero(float* a, int n) {
    int i = blockIdx.x * 256 + threadIdx.x;
    if (i < n) a[i] = 0.f;
}

__global__ void k_iijj(int* iijj) {
    int p = threadIdx.x;
    if (p >= PP) return;
    int i = 0, p0 = 0;
    while (p >= p0 + (NN - 1 - i)) { p0 += NN - 1 - i; i++; }
    iijj[p] = i;
    iijj[PP + p] = i + 1 + (p - p0);
}

// q1 effective bias: q1_b[o] + sum over odd k of q1_w[o][k]  (PE at pos 0)
__global__ void k_q1beff(const float* q1w, const float* q1b, float* beff) {
    int o = blockIdx.x * 256 + threadIdx.x;
    if (o >= Q1O) return;
    float a = q1b[o];
    for (int k = 1; k < QIN; k += 2) a += q1w[o * QIN + k];
    beff[o] = a;
}

__global__ void k_addb(const float* a, const float* b, float* c, int n) {
    int i = blockIdx.x * 256 + threadIdx.x;
    if (i < n) c[i] = a[i] + b[i];
}

// ---------------- transpose (sub-range of columns) ----------------
__global__ void k_transpose(const float* __restrict__ src, float* __restrict__ dst,
                            int R, int C, int c0, int csub) {
    __shared__ float tile[32][33];
    int cb = blockIdx.x * 32, rb = blockIdx.y * 32;
    for (int dy = threadIdx.y; dy < 32; dy += 8) {
        int r = rb + dy, c = cb + threadIdx.x;
        if (r < R && c < csub) tile[dy][threadIdx.x] = src[(size_t)r * C + c0 + c];
    }
    __syncthreads();
    for (int dy = threadIdx.y; dy < 32; dy += 8) {
        int c = cb + dy, r = rb + threadIdx.x;
        if (c < csub && r < R) dst[(size_t)c * R + r] = tile[threadIdx.x][dy];
    }
}

// ---------------- pack fp32 [NR x K from col0] -> blocked bf16 hi/lo tiles ----------------
__global__ void k_pack(const float* __restrict__ src, int ld, int col0, int NR, int K,
                       short* __restrict__ D) {
    int kt = blockIdx.x, mt = blockIdx.y, KT = gridDim.x;
    size_t tb = ((size_t)mt * KT + kt) * (2 * TPLANE);
    for (int idx = threadIdx.x; idx < 1024; idx += 256) {
        int rowin = idx >> 3, k4 = (idx & 7) << 2;
        int r = mt * 128 + rowin, k = kt * 32 + k4;
        float4 v = {0.f, 0.f, 0.f, 0.f};
        if (r < NR && k < K) v = *(const float4*)(src + (size_t)r * ld + col0 + k);
        size_t o = tb + rowin * TROW + k4;
        split4(v, D + o, D + o + TPLANE);
    }
}

// single-plane (pure bf16) variant: dst [mt][kt][128][40]
__global__ void k_pack1(const float* __restrict__ src, int ld, int col0, int NR, int K,
                        short* __restrict__ D) {
    int kt = blockIdx.x, mt = blockIdx.y, KT = gridDim.x;
    size_t tb = ((size_t)mt * KT + kt) * TPLANE;
    for (int idx = threadIdx.x; idx < 1024; idx += 256) {
        int rowin = idx >> 3, k4 = (idx & 7) << 2;
        int r = mt * 128 + rowin, k = kt * 32 + k4;
        float4 v = {0.f, 0.f, 0.f, 0.f};
        if (r < NR && k < K) v = *(const float4*)(src + (size_t)r * ld + col0 + k);
        hi4(v, D + tb + rowin * TROW + k4);
    }
}

// ---------------- pack w_hh gate-interleaved, PURE bf16, for fused LSTM ----------------
// wf[blk 375][kt 47][16 rows][32 k] shorts. row = h_loc*4 + gate,
// h_glob = blk*4 + h_loc. K pads zero.
__global__ void k_pack_wf(const float* __restrict__ whh, short* __restrict__ wf) {
    int kt = blockIdx.x, blk = blockIdx.y;
    size_t tb = ((size_t)blk * LKT + kt) * LTILE_W;
    int t = threadIdx.x;                  // 128 threads: one float4 each
    int row = t >> 3, k4 = (t & 7) << 2;
    int g = row & 3, h_glob = blk * 4 + (row >> 2);
    int k = kt * 32 + k4;
    float4 v = {0.f, 0.f, 0.f, 0.f};
    if (k < HH) {
        int j = g * HH + h_glob;
        v = *(const float4*)(whh + (size_t)j * HH + k);
    }
    hi4(v, wf + tb + row * 32 + k4);
}

// ---------------- sort along parts axis: bitonic network (static indices) ----------------
__global__ void k_sort(const float* __restrict__ x, float* __restrict__ seq) {
    int tid = blockIdx.x * 256 + threadIdx.x;
    if (tid >= BB * EE) return;
    int b = tid / EE, e = tid % EE;
    float v[NN];
#pragma unroll
    for (int n = 0; n < NN; n++) v[n] = x[(b * NN + n) * EE + e];
#pragma unroll
    for (int kk = 2; kk <= NN; kk <<= 1) {
#pragma unroll
        for (int jj = kk >> 1; jj > 0; jj >>= 1) {
#pragma unroll
            for (int i = 0; i < NN; i++) {
                int l = i ^ jj;
                if (l > i) {
                    bool up = (i & kk) == 0;
                    float a = v[i], c = v[l];
                    bool sw = up ? (a > c) : (a < c);
                    float lo = sw ? c : a, hi = sw ? a : c;
                    v[i] = lo; v[l] = hi;
                }
            }
        }
    }
#pragma unroll
    for (int n = 0; n < NN; n++) seq[(n * BB + b) * EE + e] = v[n];
}

// ---------------- pairs gather, writes single-plane bf16 tiles directly ----------------
__global__ void k_pairs(const float* __restrict__ x, const int* __restrict__ iijj,
                        short* __restrict__ P) {
    int idx = blockIdx.x * 256 + threadIdx.x; // quad index
    int r = idx >> 7;
    if (r >= ROWS) return;
    int q = idx & 127, k = q << 2;
    int b = r / PP, p = r - b * PP;
    int part = (k < EE) ? iijj[p] : iijj[PP + p];
    float4 v = *(const float4*)(x + (size_t)(b * NN + part) * EE + (k & (EE - 1)));
    int mt = r >> 7, rowin = r & 127, kt = k >> 5, k4 = k & 31;
    size_t o = ((size_t)mt * 16 + kt) * TPLANE + rowin * TROW + k4;
    hi4(v, P + o);
}

// ---------------- templated MFMA GEMM ----------------
// APL/BPL: operand planes (2 = hi/lo bf16x3 style, 1 = pure bf16).
// <1,1,*>: DEEP-PIPELINED path — 3 LDS buffers, counted s_waitcnt vmcnt(5) + raw
// s_barrier per k-step (T3/T4): prefetch loads stay in flight ACROSS barriers, the
// drain-all stall (measured ~3400 cyc/k-step) disappears. Even staging: 5 loads/wave.
// <2,2,*>: classic drain path (depth-3 LDS would not fit).
// PPL: pack-out planes. XCD-grouped 1D grid: grid = 8 * NT * ceil(MT/8).
// cmode 0: C[row][col] = act(acc + bias[col] + pbm). cmode 1: transposed xgT write.
template<int APL, int BPL, int PPL>
__global__ __launch_bounds__(256, 2)
void k_gemm_t(const short* __restrict__ Ap, int AKT, const short* __restrict__ Bp,
              const float* __restrict__ bias, const float* __restrict__ pbm,
              float* __restrict__ Cf32, short* __restrict__ P, int PKT,
              int M, int K, int N, int relu, int cmode) {
    const int ATS = APL * TPLANE;          // A tile shorts
    const int BTS = BPL * TPLANE;          // B tile shorts
    constexpr bool PIPE = (APL == 1 && BPL == 1);
    constexpr int DEPTH = PIPE ? 3 : 2;
    __shared__ __align__(16) short lds[DEPTH][(APL + BPL) * TPLANE];

    int MT = M >> 7, NT = (N + 127) >> 7;
    int bid = blockIdx.x;
    int xcd = bid & 7, rr = bid >> 3;
    int nt = rr % NT, mtc = rr / NT;
    int mt = mtc * 8 + xcd;
    if (mt >= MT) return;

    int tid = threadIdx.x;
    int lane = tid & 63, w = tid >> 6;
    int wr = w >> 1, wc = w & 1;
    int ksteps = (K + 31) >> 5;

    const short* gA = Ap + (size_t)mt * AKT * ATS;
    const short* gB = Bp + (size_t)nt * ksteps * BTS;

    f32x4 acc[4][4];
#pragma unroll
    for (int mi = 0; mi < 4; mi++)
#pragma unroll
        for (int ni = 0; ni < 4; ni++) acc[mi][ni] = (f32x4){0.f, 0.f, 0.f, 0.f};

    int l15 = lane & 15;
    int kc8 = (lane >> 4) << 3;

    if constexpr (PIPE) {
        // even distribution: chunks 0..9 = A, 10..19 = B; wave w stages [w*5, w*5+5)
#define STAGE3(bufi, kt) do { \
            _Pragma("unroll") \
            for (int i_ = 0; i_ < 5; i_++) { \
                int c_ = w * 5 + i_; \
                const short* s_ = (c_ < 10) \
                    ? gA + (size_t)(kt) * ATS + (c_ << 9) + lane * 8 \
                    : gB + (size_t)(kt) * BTS + ((c_ - 10) << 9) + lane * 8; \
                ASYNC16(&lds[bufi][c_ << 9], s_); \
            } \
        } while (0)

        STAGE3(0, 0);
        if (ksteps > 1) STAGE3(1, 1);

        int cbuf = 0, sbuf = 2;
        for (int kt = 0; kt < ksteps; kt++) {
            // wait only for THIS k-step's loads (5 newest may stay in flight)
            if (kt + 1 < ksteps) asm volatile("s_waitcnt vmcnt(5)" ::: "memory");
            else                 asm volatile("s_waitcnt vmcnt(0)" ::: "memory");
            __builtin_amdgcn_s_barrier();

            const short* LA = &lds[cbuf][0];
            const short* LB = &lds[cbuf][TPLANE];
            bf16x8 ah[4];
#pragma unroll
            for (int mi = 0; mi < 4; mi++)
                ah[mi] = *(const bf16x8*)(LA + (wr * 64 + mi * 16 + l15) * TROW + kc8);
#pragma unroll
            for (int ni = 0; ni < 4; ni++) {
                bf16x8 bh = *(const bf16x8*)(LB + (wc * 64 + ni * 16 + l15) * TROW + kc8);
#pragma unroll
                for (int mi = 0; mi < 4; mi++)
                    acc[mi][ni] = __builtin_amdgcn_mfma_f32_16x16x32_bf16(ah[mi], bh, acc[mi][ni], 0, 0, 0);
            }
            if (kt + 2 < ksteps) STAGE3(sbuf, kt + 2);
            cbuf = (cbuf == 2) ? 0 : cbuf + 1;
            sbuf = (sbuf == 2) ? 0 : sbuf + 1;
        }
#undef STAGE3
    } else {
#define STAGE(bufi, kt) do { \
            const short* sa_ = gA + (size_t)(kt) * ATS + lane * 8; \
            const short* sb_ = gB + (size_t)(kt) * BTS + lane * 8; \
            for (int c_ = w; c_ < ATS / 512; c_ += 4) \
                ASYNC16(&lds[bufi][c_ * 512], sa_ + c_ * 512); \
            for (int c_ = w; c_ < BTS / 512; c_ += 4) \
                ASYNC16(&lds[bufi][ATS + c_ * 512], sb_ + c_ * 512); \
        } while (0)

        STAGE(0, 0);
        __syncthreads();
        int buf = 0;
        for (int kt = 0; kt < ksteps; kt++) {
            if (kt + 1 < ksteps) STAGE(buf ^ 1, kt + 1);
            const short* LA = &lds[buf][0];
            const short* LB = &lds[buf][ATS];
            bf16x8 ah[4], al[4];
#pragma unroll
            for (int mi = 0; mi < 4; mi++) {
                int o = (wr * 64 + mi * 16 + l15) * TROW + kc8;
                ah[mi] = *(const bf16x8*)(LA + o);
                if constexpr (APL == 2) al[mi] = *(const bf16x8*)(LA + TPLANE + o);
            }
#pragma unroll
            for (int ni = 0; ni < 4; ni++) {
                int o = (wc * 64 + ni * 16 + l15) * TROW + kc8;
                bf16x8 bh = *(const bf16x8*)(LB + o);
                bf16x8 bl;
                if constexpr (BPL == 2) bl = *(const bf16x8*)(LB + TPLANE + o);
#pragma unroll
                for (int mi = 0; mi < 4; mi++) {
                    acc[mi][ni] = __builtin_amdgcn_mfma_f32_16x16x32_bf16(ah[mi], bh, acc[mi][ni], 0, 0, 0);
                    if constexpr (BPL == 2)
                        acc[mi][ni] = __builtin_amdgcn_mfma_f32_16x16x32_bf16(ah[mi], bl, acc[mi][ni], 0, 0, 0);
                    if constexpr (APL == 2)
                        acc[mi][ni] = __builtin_amdgcn_mfma_f32_16x16x32_bf16(al[mi], bh, acc[mi][ni], 0, 0, 0);
                }
            }
            __syncthreads();
            buf ^= 1;
        }
#undef STAGE
    }

    const int PTS = PPL * TPLANE;
#pragma unroll
    for (int ni = 0; ni < 4; ni++) {
        int col = nt * 128 + wc * 64 + ni * 16 + l15;
        float bb = (cmode == 0 && bias && col < N) ? bias[col] : 0.f;
#pragma unroll
        for (int mi = 0; mi < 4; mi++) {
            int rbase = mt * 128 + wr * 64 + mi * 16 + ((lane >> 4) << 2);
#pragma unroll
            for (int r4 = 0; r4 < 4; r4++) {
                int row = rbase + r4;
                float v = acc[mi][ni][r4];
                if (cmode == 1) {
                    if (row < G4)
                        Cf32[(size_t)(col >> 5) * (G4 * BB) + (size_t)row * BB + (col & 31)]
                            = v + bias[row];
                    continue;
                }
                v += bb;
                if (pbm && col < N) v += pbm[(size_t)(row / PP) * N + col];
                if (relu) v = fmaxf(v, 0.f);
                if (Cf32 && col < N) Cf32[(size_t)row * N + col] = v;
                if (P) {
                    unsigned h = bf16h(v);
                    int kt2 = col >> 5, kin = col & 31, rowin = row & 127, mtt = row >> 7;
                    size_t o = ((size_t)mtt * PKT + kt2) * PTS + rowin * TROW + kin;
                    P[o] = (short)(h >> 16);
                    if constexpr (PPL == 2) {
                        unsigned l = bf16h(v - __uint_as_float(h));
                        P[o + TPLANE] = (short)(l >> 16);
                    }
                }
            }
        }
    }
}

// ---------------- fused LSTM step: 375 blocks x 8 waves, k-split 4-way ----------------
// h SINGLE-plane bf16 (halves the dominant per-step cross-XCD h-read volume,
// 1 MFMA per k-tile). Block owns h [blk*4, blk*4+4). wave = (ks, mi).
// LDS-reduce ks>0 partials into ks=0. acc init = xgT preactivation.
// h writes non-temporal; fp32 ht only on last step. Weights PURE bf16, L2-resident.
__global__ __launch_bounds__(512, 1)
void k_lstm_step(const short* __restrict__ wf, const short* __restrict__ hbuf_r,
                 short* __restrict__ hbuf_w, const float* __restrict__ xgT_n,
                 float* __restrict__ ct, float* __restrict__ ht, int writeht) {
    __shared__ f32x4 red[3][2][64];
    int tid = threadIdx.x, lane = tid & 63, wave = tid >> 6;
    int ks = wave >> 1, mi = wave & 1;
    int blk = blockIdx.x;
    int l15 = lane & 15, bg = lane >> 4;
    int kc8 = bg << 3;
    int n = l15, g = n & 3;
    int h_glob = blk * 4 + (n >> 2);
    int kt0 = ks * 12, ktend = (ks == 3) ? LKT : (kt0 + 12);

    f32x4 acc = {0.f, 0.f, 0.f, 0.f};
    if (ks == 0)
        acc = *(const f32x4*)(xgT_n + (size_t)(g * HH + h_glob) * BB + mi * 16 + bg * 4);

    const short* wp0 = wf + (size_t)blk * HSZW + l15 * 32 + kc8;
    const short* hp0 = hbuf_r + (mi * 16 + l15) * 32 + kc8;

    // depth-3 software pipeline, named-register rotation
    bf16x8 a0 = *(const bf16x8*)(hp0 + (size_t)kt0 * LTILE);
    bf16x8 b0 = *(const bf16x8*)(wp0 + (size_t)kt0 * LTILE_W);
    bf16x8 a1 = *(const bf16x8*)(hp0 + (size_t)(kt0 + 1) * LTILE);
    bf16x8 b1 = *(const bf16x8*)(wp0 + (size_t)(kt0 + 1) * LTILE_W);
    bf16x8 a2 = *(const bf16x8*)(hp0 + (size_t)(kt0 + 2) * LTILE);
    bf16x8 b2 = *(const bf16x8*)(wp0 + (size_t)(kt0 + 2) * LTILE_W);
    for (int kt = kt0; kt < ktend; kt++) {
        bf16x8 a3, b3;
        if (kt + 3 < ktend) {
            a3 = *(const bf16x8*)(hp0 + (size_t)(kt + 3) * LTILE);
            b3 = *(const bf16x8*)(wp0 + (size_t)(kt + 3) * LTILE_W);
        }
        acc = __builtin_amdgcn_mfma_f32_16x16x32_bf16(a0, b0, acc, 0, 0, 0);
        a0 = a1; b0 = b1;
        a1 = a2; b1 = b2;
        a2 = a3; b2 = b3;
    }

    // reduce ks>0 partials into ks=0 waves
    if (ks > 0) red[ks - 1][mi][lane] = acc;
    __syncthreads();
    if (ks > 0) return;
    acc += red[0][mi][lane] + red[1][mi][lane] + red[2][mi][lane];

    // gather the 4 gates across the 4-lane group (lane n, n^1, n^2, n^3)
    float gg[4][4];
#pragma unroll
    for (int r = 0; r < 4; r++) {
        float a = acc[r];
        gg[0][r] = a;
        gg[1][r] = __shfl_xor(a, 1);
        gg[2][r] = __shfl_xor(a, 2);
        gg[3][r] = __shfl_xor(a, 3);
    }

    if ((n & 3) == 0) {
        int kth = h_glob >> 5, kin = h_glob & 31;
#pragma unroll
        for (int r = 0; r < 4; r++) {
            int b = mi * 16 + bg * 4 + r;
            float ci = ct[h_glob * BB + b];
            float cn = sigm(gg[1][r]) * ci + sigm(gg[0][r]) * tanhf(gg[2][r]);
            ct[h_glob * BB + b] = cn;
            float hv = sigm(gg[3][r]) * tanhf(cn);
            if (writeht) ht[h_glob * BB + b] = hv;
            unsigned hh = bf16h(hv);
            size_t o = (size_t)kth * LTILE + b * 32 + kin;
            __builtin_nontemporal_store((short)(hh >> 16), &hbuf_w[o]);
        }
    }
}

// ---------------- plan-side e1 bias (plan in ht layout [h][b]) ----------------
__global__ void k_pb(const float* __restrict__ ht, const float* __restrict__ e1at,
                     const float* __restrict__ e1b, float* __restrict__ pb) {
    __shared__ float ps[HH];
    int b = blockIdx.y;
    for (int idx = threadIdx.x; idx < HH; idx += 256) ps[idx] = ht[(size_t)idx * BB + b];
    __syncthreads();
    int o = blockIdx.x * 256 + threadIdx.x;
    if (o >= EV1) return;
    float acc = e1b[o];
    for (int k = 0; k < HH; k++) acc += ps[k] * e1at[(size_t)k * EV1 + o];
    pb[b * EV1 + o] = acc;
}

// ---------------- fused e3 + e4 tail ----------------
__global__ void k_e34(const float* __restrict__ e2out, const float* __restrict__ e3t,
                      const float* __restrict__ e3b, const float* __restrict__ e4w,
                      const float* __restrict__ e4b, float* __restrict__ out) {
    __shared__ float wt[EV2 * EV3];
    for (int idx = threadIdx.x; idx < EV2 * EV3; idx += 256) wt[idx] = e3t[idx];
    __syncthreads();
    int r = blockIdx.x * 256 + threadIdx.x;
    if (r >= ROWS) return;
    float h3[EV3];
#pragma unroll
    for (int o3 = 0; o3 < EV3; o3++) h3[o3] = e3b[o3];
    for (int k = 0; k < EV2; k++) {
        float v = e2out[(size_t)r * EV2 + k];
#pragma unroll
        for (int o3 = 0; o3 < EV3; o3++) h3[o3] += v * wt[k * EV3 + o3];
    }
    float acc = e4b[0];
#pragma unroll
    for (int o3 = 0; o3 < EV3; o3++) acc += fmaxf(h3[o3], 0.f) * e4w[o3];
    out[r] = fmaxf(acc, 0.f);
}

// ---------------- host launch ----------------
extern "C" void kernel_launch(void* const* d_in, const int* in_sizes, int n_in,
                              void* d_out, int out_size, void* d_ws, size_t ws_size,
                              hipStream_t stream) {
    const float* x    = (const float*)d_in[0];
    const float* w_ih = (const float*)d_in[1];
    const float* w_hh = (const float*)d_in[2];
    const float* b_ih = (const float*)d_in[3];
    const float* b_hh = (const float*)d_in[4];
    const float* q1_w = (const float*)d_in[5];
    const float* q1_b = (const float*)d_in[6];
    const float* q2_w = (const float*)d_in[7];
    const float* q2_b = (const float*)d_in[8];
    const float* e1_w = (const float*)d_in[9];
    const float* e1_b = (const float*)d_in[10];
    const float* e2_w = (const float*)d_in[11];
    const float* e2_b = (const float*)d_in[12];
    const float* e3_w = (const float*)d_in[13];
    const float* e3_b = (const float*)d_in[14];
    const float* e4_w = (const float*)d_in[15];
    const float* e4_b = (const float*)d_in[16];
    float* out = (float*)d_out;
    float* ws = (float*)d_ws;

    // ---- workspace layout (float offsets) ----
    size_t off = 0;
    float* seq    = ws + off; off += (size_t)NN * BB * EE;   // 262,144
    size_t regionA = off; off += 23000000;
    short* wf       = (short*)(ws + regionA);                // 375*47*512 = 9,024,000 sh
    short* seq_p    = (short*)(ws + regionA + 4600000);      // 655,360 sh
    short* wih_p    = (short*)(ws + regionA + 5000000);      // 3,850,240 sh
    short* pairs_p  = (short*)(ws + regionA);                // 10,158,080 sh (bf16)
    short* q1out_p  = (short*)(ws + regionA + 10200000);     // 12,697,600 sh (bf16)
    short* e1out_p  = (short*)(ws + regionA);                // 20,316,160 sh (bf16)
    float* e2out    = ws + regionA + 20400000;               // 1,587,200 fl
    float* xgT    = ws + off; off += 7618560;                // 6,144,000 fl; q2out_p alias
    short* q2out_p  = (short*)xgT;                           // 7,618,560 sh (bf16)
    float* ht     = ws + off; off += BH;
    float* ct     = ws + off; off += BH;                     // ct + hbuf contiguous: one zero
    short* hbuf   = (short*)(ws + off); off += 48128;        // 2 x HSZ shorts (single plane)
    short* q1w_p  = (short*)(ws + off); off += 409600;       // single-plane
    short* q2w_p  = (short*)(ws + off); off += 291840;       // single-plane
    short* e1w_p  = (short*)(ws + off); off += 409600;       // single-plane
    short* e2w_p  = (short*)(ws + off); off += 163840;       // single-plane
    float* e1at   = ws + off; off += (size_t)HH * EV1;
    float* e3t    = ws + off; off += 1024;
    float* pb     = ws + off; off += BB * EV1;
    float* q1beff = ws + off; off += 1024;
    float* bsum   = ws + off; off += 6016;
    int*   iijj   = (int*)(ws + off); off += 1024;

    dim3 tb(32, 8);

    // init (ct and hbuf are contiguous -> single zero launch: 48000 + 48128 floats)
    k_iijj<<<1, 512, 0, stream>>>(iijj);
    k_q1beff<<<3, 256, 0, stream>>>(q1_w, q1_b, q1beff);
    k_addb<<<24, 256, 0, stream>>>(b_ih, b_hh, bsum, G4);
    k_zero<<<376, 256, 0, stream>>>(ct, BH + 48128);

    // weight transforms
    k_pack_wf<<<dim3(LKT, LBLK), 128, 0, stream>>>(w_hh, wf);
    k_transpose<<<dim3(47, 32), tb, 0, stream>>>(e1_w, e1at, EV1, HH + QO, 0, HH);
    k_transpose<<<dim3(4, 1), tb, 0, stream>>>(e3_w, e3t, EV3, EV2, 0, EV2);
    k_pack<<<dim3(8, 47), 256, 0, stream>>>(w_ih, EE, 0, G4, EE, wih_p);
    k_pack1<<<dim3(16, 5), 256, 0, stream>>>(q1_w, QIN, 0, Q1O, QIN, q1w_p);
    k_pack1<<<dim3(19, 3), 256, 0, stream>>>(q2_w, Q1O, 0, QO, Q1O, q2w_p);
    k_pack1<<<dim3(10, 8), 256, 0, stream>>>(e1_w, HH + QO, HH, EV1, QO, e1w_p);
    k_pack1<<<dim3(32, 1), 256, 0, stream>>>(e2_w, EV1, 0, EV2, EV1, e2w_p);

    // sort + pack seq; xgT = (w_ih @ seq^T) + bsum written DIRECTLY in [n][j][b]
    k_sort<<<32, 256, 0, stream>>>(x, seq);
    k_pack<<<dim3(8, 8), 256, 0, stream>>>(seq, EE, 0, 1024, EE, seq_p);
    k_gemm_t<2, 2, 1><<<8 * 8 * 6, 256, 0, stream>>>(wih_p, 8, seq_p, bsum, nullptr,
                                                     xgT, nullptr, 0, 6016, EE, 1024, 0, 1);

    // LSTM: 32 fused steps, double-buffered single-plane h (kernel-boundary coherence)
    for (int nstep = 0; nstep < NN; nstep++) {
        const short* hr = hbuf + (size_t)(nstep & 1) * HSZ;
        short* hw = hbuf + (size_t)((nstep + 1) & 1) * HSZ;
        k_lstm_step<<<LBLK, 512, 0, stream>>>(wf, hr, hw,
                                              xgT + (size_t)nstep * (G4 * BB), ct, ht,
                                              nstep == NN - 1);
    }

    // evaluator plan-side bias (includes e1_b)
    k_pb<<<dim3(4, BB), 256, 0, stream>>>(ht, e1at, e1_b, pb);

    // pair MLP (packed pipeline; pairs_p overwrites dead wf — after LSTM)
    k_pairs<<<7936, 256, 0, stream>>>(x, iijj, pairs_p);
    k_gemm_t<1, 1, 1><<<8 * 5 * 16, 256, 0, stream>>>(pairs_p, 16, q1w_p, q1beff, nullptr,
                                                      nullptr, q1out_p, 20, ROWS, QIN, Q1O, 1, 0);
    k_gemm_t<1, 1, 1><<<8 * 3 * 16, 256, 0, stream>>>(q1out_p, 20, q2w_p, q2_b, nullptr,
                                                      nullptr, q2out_p, 12, ROWS, Q1O, QO, 1, 0);
    k_gemm_t<1, 1, 1><<<8 * 8 * 16, 256, 0, stream>>>(q2out_p, 12, e1w_p, nullptr, pb,
                                                      nullptr, e1out_p, 32, ROWS, QO, EV1, 1, 0);
    k_gemm_t<1, 1, 1><<<8 * 1 * 16, 256, 0, stream>>>(e1out_p, 32, e2w_p, e2_b, nullptr,
                                                      e2out, nullptr, 0, ROWS, EV1, EV2, 1, 0);
    k_e34<<<62, 256, 0, stream>>>(e2out, e3t, e3_b, e4_w, e4_b, out);
}

// Round 12
// 708.057 us; speedup vs baseline: 1.2653x; 1.0828x over previous
//
#include <hip/hip_runtime.h>
#include <math.h>

// Problem dims
#define BB 32
#define NN 32
#define EE 256
#define HH 1500
#define G4 6000      // 4*HH
#define QIN 512
#define Q1O 600
#define QO 300
#define EV1 1000
#define EV2 100
#define EV3 10
#define PP 496       // N*(N-1)/2
#define ROWS (BB*PP) // 15872
#define BH (BB*HH)   // 48000

// Packed GEMM operand tile: [planes][128 rows][40 shorts]; plane = 5120 shorts
#define TROW 40
#define TPLANE (128 * TROW)   // 5120 shorts per plane

// LSTM fused geometry: 375 blocks x 4 h-indices, K padded to 47*32=1504
#define LKT 47
#define LBLK 375
#define LTILE 1024            // h-buffer shorts per kt: [32 rows][32 k] SINGLE plane
#define HSZ (LKT * LTILE)     // 48128 shorts per h buffer
#define LTILE_W 512           // wf shorts per (blk,kt): [16 rows][32 k] single plane
#define HSZW (LKT * LTILE_W)  // 24064 shorts per block slice

typedef __attribute__((ext_vector_type(8))) short bf16x8;
typedef __attribute__((ext_vector_type(4))) float f32x4;

__device__ __forceinline__ float sigm(float x) { return 1.f / (1.f + expf(-x)); }

// RNE round to bf16, kept as fp32 bit pattern (low 16 bits zero)
__device__ __forceinline__ unsigned bf16h(float x) {
    unsigned u = __float_as_uint(x);
    return (u + 0x7FFFu + ((u >> 16) & 1u)) & 0xFFFF0000u;
}

// split float4 -> hi/lo bf16 quads, 8B store each
__device__ __forceinline__ void split4(float4 v, short* hp, short* lp) {
    unsigned h0 = bf16h(v.x), h1 = bf16h(v.y), h2 = bf16h(v.z), h3 = bf16h(v.w);
    float r0 = v.x - __uint_as_float(h0);
    float r1 = v.y - __uint_as_float(h1);
    float r2 = v.z - __uint_as_float(h2);
    float r3 = v.w - __uint_as_float(h3);
    unsigned l0 = bf16h(r0), l1 = bf16h(r1), l2 = bf16h(r2), l3 = bf16h(r3);
    uint2 hw, lw;
    hw.x = (h0 >> 16) | (h1 & 0xFFFF0000u);
    hw.y = (h2 >> 16) | (h3 & 0xFFFF0000u);
    lw.x = (l0 >> 16) | (l1 & 0xFFFF0000u);
    lw.y = (l2 >> 16) | (l3 & 0xFFFF0000u);
    *(uint2*)hp = hw;
    *(uint2*)lp = lw;
}

// hi-plane only version (pure bf16)
__device__ __forceinline__ void hi4(float4 v, short* hp) {
    unsigned h0 = bf16h(v.x), h1 = bf16h(v.y), h2 = bf16h(v.z), h3 = bf16h(v.w);
    uint2 hw;
    hw.x = (h0 >> 16) | (h1 & 0xFFFF0000u);
    hw.y = (h2 >> 16) | (h3 & 0xFFFF0000u);
    *(uint2*)hp = hw;
}

// async 16B global -> LDS (dest wave-uniform; HW adds lane*16B)
#define ASYNC16(dst, src) \
    __builtin_amdgcn_global_load_lds((const __attribute__((address_space(1))) unsigned*)(src), \
                                     (__attribute__((address_space(3))) unsigned*)(dst), 16, 0, 0)

// ---------------- init helpers ----------------
__global__ void k_zero(float* a, int n) {
    int i = blockIdx.x * 256 + threadIdx.x;
    if (i < n) a[i] = 0.f;
}

__global__ void k_iijj(int* iijj) {
    int p = threadIdx.x;
    if (p >= PP) return;
    int i = 0, p0 = 0;
    while (p >= p0 + (NN - 1 - i)) { p0 += NN - 1 - i; i++; }
    iijj[p] = i;
    iijj[PP + p] = i + 1 + (p - p0);
}

// q1 effective bias: q1_b[o] + sum over odd k of q1_w[o][k]  (PE at pos 0)
__global__ void k_q1beff(const float* q1w, const float* q1b, float* beff) {
    int o = blockIdx.x * 256 + threadIdx.x;
    if (o >= Q1O) return;
    float a = q1b[o];
    for (int k = 1; k < QIN; k += 2) a += q1w[o * QIN + k];
    beff[o] = a;
}

__global__ void k_addb(const float* a, const float* b, float* c, int n) {
    int i = blockIdx.x * 256 + threadIdx.x;
    if (i < n) c[i] = a[i] + b[i];
}

// ---------------- transpose (sub-range of columns) ----------------
__global__ void k_transpose(const float* __restrict__ src, float* __restrict__ dst,
                            int R, int C, int c0, int csub) {
    __shared__ float tile[32][33];
    int cb = blockIdx.x * 32, rb = blockIdx.y * 32;
    for (int dy = threadIdx.y; dy < 32; dy += 8) {
        int r = rb + dy, c = cb + threadIdx.x;
        if (r < R && c < csub) tile[dy][threadIdx.x] = src[(size_t)r * C + c0 + c];
    }
    __syncthreads();
    for (int dy = threadIdx.y; dy < 32; dy += 8) {
        int c = cb + dy, r = rb + threadIdx.x;
        if (c < csub && r < R) dst[(size_t)c * R + r] = tile[threadIdx.x][dy];
    }
}

// ---------------- pack fp32 [NR x K from col0] -> blocked bf16 hi/lo tiles ----------------
__global__ void k_pack(const float* __restrict__ src, int ld, int col0, int NR, int K,
                       short* __restrict__ D) {
    int kt = blockIdx.x, mt = blockIdx.y, KT = gridDim.x;
    size_t tb = ((size_t)mt * KT + kt) * (2 * TPLANE);
    for (int idx = threadIdx.x; idx < 1024; idx += 256) {
        int rowin = idx >> 3, k4 = (idx & 7) << 2;
        int r = mt * 128 + rowin, k = kt * 32 + k4;
        float4 v = {0.f, 0.f, 0.f, 0.f};
        if (r < NR && k < K) v = *(const float4*)(src + (size_t)r * ld + col0 + k);
        size_t o = tb + rowin * TROW + k4;
        split4(v, D + o, D + o + TPLANE);
    }
}

// single-plane (pure bf16) variant: dst [mt][kt][128][40]
__global__ void k_pack1(const float* __restrict__ src, int ld, int col0, int NR, int K,
                        short* __restrict__ D) {
    int kt = blockIdx.x, mt = blockIdx.y, KT = gridDim.x;
    size_t tb = ((size_t)mt * KT + kt) * TPLANE;
    for (int idx = threadIdx.x; idx < 1024; idx += 256) {
        int rowin = idx >> 3, k4 = (idx & 7) << 2;
        int r = mt * 128 + rowin, k = kt * 32 + k4;
        float4 v = {0.f, 0.f, 0.f, 0.f};
        if (r < NR && k < K) v = *(const float4*)(src + (size_t)r * ld + col0 + k);
        hi4(v, D + tb + rowin * TROW + k4);
    }
}

// ---------------- pack w_hh gate-interleaved, PURE bf16, for fused LSTM ----------------
__global__ void k_pack_wf(const float* __restrict__ whh, short* __restrict__ wf) {
    int kt = blockIdx.x, blk = blockIdx.y;
    size_t tb = ((size_t)blk * LKT + kt) * LTILE_W;
    int t = threadIdx.x;                  // 128 threads: one float4 each
    int row = t >> 3, k4 = (t & 7) << 2;
    int g = row & 3, h_glob = blk * 4 + (row >> 2);
    int k = kt * 32 + k4;
    float4 v = {0.f, 0.f, 0.f, 0.f};
    if (k < HH) {
        int j = g * HH + h_glob;
        v = *(const float4*)(whh + (size_t)j * HH + k);
    }
    hi4(v, wf + tb + row * 32 + k4);
}

// ---------------- sort along parts axis: bitonic network (static indices) ----------------
__global__ void k_sort(const float* __restrict__ x, float* __restrict__ seq) {
    int tid = blockIdx.x * 256 + threadIdx.x;
    if (tid >= BB * EE) return;
    int b = tid / EE, e = tid % EE;
    float v[NN];
#pragma unroll
    for (int n = 0; n < NN; n++) v[n] = x[(b * NN + n) * EE + e];
#pragma unroll
    for (int kk = 2; kk <= NN; kk <<= 1) {
#pragma unroll
        for (int jj = kk >> 1; jj > 0; jj >>= 1) {
#pragma unroll
            for (int i = 0; i < NN; i++) {
                int l = i ^ jj;
                if (l > i) {
                    bool up = (i & kk) == 0;
                    float a = v[i], c = v[l];
                    bool sw = up ? (a > c) : (a < c);
                    float lo = sw ? c : a, hi = sw ? a : c;
                    v[i] = lo; v[l] = hi;
                }
            }
        }
    }
#pragma unroll
    for (int n = 0; n < NN; n++) seq[(n * BB + b) * EE + e] = v[n];
}

// ---------------- pairs gather, writes single-plane bf16 tiles directly ----------------
__global__ void k_pairs(const float* __restrict__ x, const int* __restrict__ iijj,
                        short* __restrict__ P) {
    int idx = blockIdx.x * 256 + threadIdx.x; // quad index
    int r = idx >> 7;
    if (r >= ROWS) return;
    int q = idx & 127, k = q << 2;
    int b = r / PP, p = r - b * PP;
    int part = (k < EE) ? iijj[p] : iijj[PP + p];
    float4 v = *(const float4*)(x + (size_t)(b * NN + part) * EE + (k & (EE - 1)));
    int mt = r >> 7, rowin = r & 127, kt = k >> 5, k4 = k & 31;
    size_t o = ((size_t)mt * 16 + kt) * TPLANE + rowin * TROW + k4;
    hi4(v, P + o);
}

// ---------------- templated MFMA GEMM ----------------
// APL/BPL: operand planes (2 = hi/lo bf16x3 style, 1 = pure bf16).
// <1,1,*>: DEEP-PIPELINED path — 4 LDS buffers, counted s_waitcnt vmcnt(10/5/0) + raw
// s_barrier per k-step (T3/T4). Pack-out epilogue assembles the blocked-tile image in
// LDS (reusing pipeline buffers) then stores coalesced uint4s — replaces the 64
// scattered 2B stores + 64 scattered pbm loads per thread that made e1 VMEM-issue-bound.
// <2,2,*>: classic drain path. cmode 1: transposed xgT write (xg GEMM only).
template<int APL, int BPL, int PPL>
__global__ __launch_bounds__(256, 2)
void k_gemm_t(const short* __restrict__ Ap, int AKT, const short* __restrict__ Bp,
              const float* __restrict__ bias, const float* __restrict__ pbm,
              float* __restrict__ Cf32, short* __restrict__ P, int PKT,
              int M, int K, int N, int relu, int cmode) {
    const int ATS = APL * TPLANE;          // A tile shorts
    const int BTS = BPL * TPLANE;          // B tile shorts
    constexpr bool PIPE = (APL == 1 && BPL == 1);
    constexpr int DEPTH = PIPE ? 4 : 2;
    __shared__ __align__(16) short lds[DEPTH][(APL + BPL) * TPLANE];  // 80 KiB both ways

    int MT = M >> 7, NT = (N + 127) >> 7;
    int bid = blockIdx.x;
    int xcd = bid & 7, rr = bid >> 3;
    int nt = rr % NT, mtc = rr / NT;
    int mt = mtc * 8 + xcd;
    if (mt >= MT) return;

    int tid = threadIdx.x;
    int lane = tid & 63, w = tid >> 6;
    int wr = w >> 1, wc = w & 1;
    int ksteps = (K + 31) >> 5;

    const short* gA = Ap + (size_t)mt * AKT * ATS;
    const short* gB = Bp + (size_t)nt * ksteps * BTS;

    f32x4 acc[4][4];
#pragma unroll
    for (int mi = 0; mi < 4; mi++)
#pragma unroll
        for (int ni = 0; ni < 4; ni++) acc[mi][ni] = (f32x4){0.f, 0.f, 0.f, 0.f};

    int l15 = lane & 15;
    int kc8 = (lane >> 4) << 3;

    if constexpr (PIPE) {
        // even distribution: chunks 0..9 = A, 10..19 = B; wave w stages [w*5, w*5+5)
#define STAGE3(bufi, kt) do { \
            _Pragma("unroll") \
            for (int i_ = 0; i_ < 5; i_++) { \
                int c_ = w * 5 + i_; \
                const short* s_ = (c_ < 10) \
                    ? gA + (size_t)(kt) * ATS + (c_ << 9) + lane * 8 \
                    : gB + (size_t)(kt) * BTS + ((c_ - 10) << 9) + lane * 8; \
                ASYNC16(&lds[bufi][c_ << 9], s_); \
            } \
        } while (0)

        STAGE3(0, 0);
        if (ksteps > 1) STAGE3(1, 1);
        if (ksteps > 2) STAGE3(2, 2);

        for (int kt = 0; kt < ksteps; kt++) {
            int ahead = ksteps - 1 - kt;
            if (ahead >= 2)      asm volatile("s_waitcnt vmcnt(10)" ::: "memory");
            else if (ahead == 1) asm volatile("s_waitcnt vmcnt(5)" ::: "memory");
            else                 asm volatile("s_waitcnt vmcnt(0)" ::: "memory");
            __builtin_amdgcn_s_barrier();

            const short* LA = &lds[kt & 3][0];
            const short* LB = &lds[kt & 3][TPLANE];
            bf16x8 ah[4];
#pragma unroll
            for (int mi = 0; mi < 4; mi++)
                ah[mi] = *(const bf16x8*)(LA + (wr * 64 + mi * 16 + l15) * TROW + kc8);
#pragma unroll
            for (int ni = 0; ni < 4; ni++) {
                bf16x8 bh = *(const bf16x8*)(LB + (wc * 64 + ni * 16 + l15) * TROW + kc8);
#pragma unroll
                for (int mi = 0; mi < 4; mi++)
                    acc[mi][ni] = __builtin_amdgcn_mfma_f32_16x16x32_bf16(ah[mi], bh, acc[mi][ni], 0, 0, 0);
            }
            if (kt + 3 < ksteps) STAGE3((kt + 3) & 3, kt + 3);
        }
#undef STAGE3
    } else {
#define STAGE(bufi, kt) do { \
            const short* sa_ = gA + (size_t)(kt) * ATS + lane * 8; \
            const short* sb_ = gB + (size_t)(kt) * BTS + lane * 8; \
            for (int c_ = w; c_ < ATS / 512; c_ += 4) \
                ASYNC16(&lds[bufi][c_ * 512], sa_ + c_ * 512); \
            for (int c_ = w; c_ < BTS / 512; c_ += 4) \
                ASYNC16(&lds[bufi][ATS + c_ * 512], sb_ + c_ * 512); \
        } while (0)

        STAGE(0, 0);
        __syncthreads();
        int buf = 0;
        for (int kt = 0; kt < ksteps; kt++) {
            if (kt + 1 < ksteps) STAGE(buf ^ 1, kt + 1);
            const short* LA = &lds[buf][0];
            const short* LB = &lds[buf][ATS];
            bf16x8 ah[4], al[4];
#pragma unroll
            for (int mi = 0; mi < 4; mi++) {
                int o = (wr * 64 + mi * 16 + l15) * TROW + kc8;
                ah[mi] = *(const bf16x8*)(LA + o);
                if constexpr (APL == 2) al[mi] = *(const bf16x8*)(LA + TPLANE + o);
            }
#pragma unroll
            for (int ni = 0; ni < 4; ni++) {
                int o = (wc * 64 + ni * 16 + l15) * TROW + kc8;
                bf16x8 bh = *(const bf16x8*)(LB + o);
                bf16x8 bl;
                if constexpr (BPL == 2) bl = *(const bf16x8*)(LB + TPLANE + o);
#pragma unroll
                for (int mi = 0; mi < 4; mi++) {
                    acc[mi][ni] = __builtin_amdgcn_mfma_f32_16x16x32_bf16(ah[mi], bh, acc[mi][ni], 0, 0, 0);
                    if constexpr (BPL == 2)
                        acc[mi][ni] = __builtin_amdgcn_mfma_f32_16x16x32_bf16(ah[mi], bl, acc[mi][ni], 0, 0, 0);
                    if constexpr (APL == 2)
                        acc[mi][ni] = __builtin_amdgcn_mfma_f32_16x16x32_bf16(al[mi], bh, acc[mi][ni], 0, 0, 0);
                }
            }
            __syncthreads();
            buf ^= 1;
        }
#undef STAGE
    }

    // ---------------- epilogue ----------------
    bool done = false;
    if constexpr (PIPE) {
        if (P) {
            // LDS-coalesced pack-out. obuf = 2 regions x [128 rows][40 shorts] in lds[0];
            // pbv (pbm slice, <=2 batches x 128 cols) in lds[1].
            short* obuf = &lds[0][0];
            float* pbv  = (float*)&lds[1][0];
            int b0 = (mt * 128) / PP;
            int thr = (b0 + 1) * PP;
            __syncthreads();                       // k-loop LDS reads complete
            if (pbm) {
                int c = nt * 128 + (tid & 127);
                int bsel = (tid < 128) ? b0 : min(b0 + 1, BB - 1);
                pbv[tid] = (c < N) ? pbm[(size_t)bsel * N + c] : 0.f;
            }
            __syncthreads();                       // pbv visible
            int bg = lane >> 4;
#pragma unroll
            for (int r = 0; r < 2; r++) {
#pragma unroll
                for (int p = 0; p < 2; p++) {
                    int ni = 2 * r + p;
                    int col = nt * 128 + wc * 64 + ni * 16 + l15;
                    int colloc = wc * 64 + ni * 16 + l15;
                    float bb = (bias && col < N) ? bias[col] : 0.f;
                    int kin = p * 16 + l15;
#pragma unroll
                    for (int mi = 0; mi < 4; mi++) {
#pragma unroll
                        for (int r4 = 0; r4 < 4; r4++) {
                            int rowin = wr * 64 + mi * 16 + (bg << 2) + r4;
                            float v = acc[mi][ni][r4] + bb;
                            if (pbm) {
                                int row = mt * 128 + rowin;
                                v += pbv[(row >= thr ? 128 : 0) + colloc];
                            }
                            if (relu) v = fmaxf(v, 0.f);
                            obuf[wc * 5120 + rowin * 40 + kin] = (short)(bf16h(v) >> 16);
                        }
                    }
                }
                __syncthreads();                   // obuf assembled
#pragma unroll
                for (int reg = 0; reg < 2; reg++) {
                    int ktg = nt * 4 + reg * 2 + r;
                    uint4* dst = (uint4*)(P + ((size_t)mt * PKT + ktg) * TPLANE);
                    const uint4* srcl = (const uint4*)(obuf + reg * 5120);
                    for (int c = tid; c < 640; c += 256) dst[c] = srcl[c];
                }
                __syncthreads();                   // before next round overwrites obuf
            }
            done = true;
        }
    }
    if (!done) {
        const int PTS = PPL * TPLANE;
#pragma unroll
        for (int ni = 0; ni < 4; ni++) {
            int col = nt * 128 + wc * 64 + ni * 16 + l15;
            float bb = (cmode == 0 && bias && col < N) ? bias[col] : 0.f;
#pragma unroll
            for (int mi = 0; mi < 4; mi++) {
                int rbase = mt * 128 + wr * 64 + mi * 16 + ((lane >> 4) << 2);
#pragma unroll
                for (int r4 = 0; r4 < 4; r4++) {
                    int row = rbase + r4;
                    float v = acc[mi][ni][r4];
                    if (cmode == 1) {
                        if (row < G4)
                            Cf32[(size_t)(col >> 5) * (G4 * BB) + (size_t)row * BB + (col & 31)]
                                = v + bias[row];
                        continue;
                    }
                    v += bb;
                    if (pbm && col < N) v += pbm[(size_t)(row / PP) * N + col];
                    if (relu) v = fmaxf(v, 0.f);
                    if (Cf32 && col < N) Cf32[(size_t)row * N + col] = v;
                    if (P) {
                        unsigned h = bf16h(v);
                        int kt2 = col >> 5, kin = col & 31, rowin = row & 127, mtt = row >> 7;
                        size_t o = ((size_t)mtt * PKT + kt2) * PTS + rowin * TROW + kin;
                        P[o] = (short)(h >> 16);
                        if constexpr (PPL == 2) {
                            unsigned l = bf16h(v - __uint_as_float(h));
                            P[o + TPLANE] = (short)(l >> 16);
                        }
                    }
                }
            }
        }
    }
}

// ---------------- fused LSTM step: 375 blocks x 8 waves, k-split 4-way ----------------
// h SINGLE-plane bf16. Block owns h [blk*4, blk*4+4). wave = (ks, mi).
// LDS-reduce ks>0 partials into ks=0. acc init = xgT preactivation.
// h writes non-temporal; fp32 ht only on last step. Weights PURE bf16, L2-resident.
__global__ __launch_bounds__(512, 1)
void k_lstm_step(const short* __restrict__ wf, const short* __restrict__ hbuf_r,
                 short* __restrict__ hbuf_w, const float* __restrict__ xgT_n,
                 float* __restrict__ ct, float* __restrict__ ht, int writeht) {
    __shared__ f32x4 red[3][2][64];
    int tid = threadIdx.x, lane = tid & 63, wave = tid >> 6;
    int ks = wave >> 1, mi = wave & 1;
    int blk = blockIdx.x;
    int l15 = lane & 15, bg = lane >> 4;
    int kc8 = bg << 3;
    int n = l15, g = n & 3;
    int h_glob = blk * 4 + (n >> 2);
    int kt0 = ks * 12, ktend = (ks == 3) ? LKT : (kt0 + 12);

    f32x4 acc = {0.f, 0.f, 0.f, 0.f};
    if (ks == 0)
        acc = *(const f32x4*)(xgT_n + (size_t)(g * HH + h_glob) * BB + mi * 16 + bg * 4);

    const short* wp0 = wf + (size_t)blk * HSZW + l15 * 32 + kc8;
    const short* hp0 = hbuf_r + (mi * 16 + l15) * 32 + kc8;

    // depth-3 software pipeline, named-register rotation
    bf16x8 a0 = *(const bf16x8*)(hp0 + (size_t)kt0 * LTILE);
    bf16x8 b0 = *(const bf16x8*)(wp0 + (size_t)kt0 * LTILE_W);
    bf16x8 a1 = *(const bf16x8*)(hp0 + (size_t)(kt0 + 1) * LTILE);
    bf16x8 b1 = *(const bf16x8*)(wp0 + (size_t)(kt0 + 1) * LTILE_W);
    bf16x8 a2 = *(const bf16x8*)(hp0 + (size_t)(kt0 + 2) * LTILE);
    bf16x8 b2 = *(const bf16x8*)(wp0 + (size_t)(kt0 + 2) * LTILE_W);
    for (int kt = kt0; kt < ktend; kt++) {
        bf16x8 a3, b3;
        if (kt + 3 < ktend) {
            a3 = *(const bf16x8*)(hp0 + (size_t)(kt + 3) * LTILE);
            b3 = *(const bf16x8*)(wp0 + (size_t)(kt + 3) * LTILE_W);
        }
        acc = __builtin_amdgcn_mfma_f32_16x16x32_bf16(a0, b0, acc, 0, 0, 0);
        a0 = a1; b0 = b1;
        a1 = a2; b1 = b2;
        a2 = a3; b2 = b3;
    }

    // reduce ks>0 partials into ks=0 waves
    if (ks > 0) red[ks - 1][mi][lane] = acc;
    __syncthreads();
    if (ks > 0) return;
    acc += red[0][mi][lane] + red[1][mi][lane] + red[2][mi][lane];

    // gather the 4 gates across the 4-lane group (lane n, n^1, n^2, n^3)
    float gg[4][4];
#pragma unroll
    for (int r = 0; r < 4; r++) {
        float a = acc[r];
        gg[0][r] = a;
        gg[1][r] = __shfl_xor(a, 1);
        gg[2][r] = __shfl_xor(a, 2);
        gg[3][r] = __shfl_xor(a, 3);
    }

    if ((n & 3) == 0) {
        int kth = h_glob >> 5, kin = h_glob & 31;
#pragma unroll
        for (int r = 0; r < 4; r++) {
            int b = mi * 16 + bg * 4 + r;
            float ci = ct[h_glob * BB + b];
            float cn = sigm(gg[1][r]) * ci + sigm(gg[0][r]) * tanhf(gg[2][r]);
            ct[h_glob * BB + b] = cn;
            float hv = sigm(gg[3][r]) * tanhf(cn);
            if (writeht) ht[h_glob * BB + b] = hv;
            unsigned hh = bf16h(hv);
            size_t o = (size_t)kth * LTILE + b * 32 + kin;
            __builtin_nontemporal_store((short)(hh >> 16), &hbuf_w[o]);
        }
    }
}

// ---------------- plan-side e1 bias (plan in ht layout [h][b]) ----------------
__global__ void k_pb(const float* __restrict__ ht, const float* __restrict__ e1at,
                     const float* __restrict__ e1b, float* __restrict__ pb) {
    __shared__ float ps[HH];
    int b = blockIdx.y;
    for (int idx = threadIdx.x; idx < HH; idx += 256) ps[idx] = ht[(size_t)idx * BB + b];
    __syncthreads();
    int o = blockIdx.x * 256 + threadIdx.x;
    if (o >= EV1) return;
    float acc = e1b[o];
    for (int k = 0; k < HH; k++) acc += ps[k] * e1at[(size_t)k * EV1 + o];
    pb[b * EV1 + o] = acc;
}

// ---------------- fused e3 + e4 tail ----------------
__global__ void k_e34(const float* __restrict__ e2out, const float* __restrict__ e3t,
                      const float* __restrict__ e3b, const float* __restrict__ e4w,
                      const float* __restrict__ e4b, float* __restrict__ out) {
    __shared__ float wt[EV2 * EV3];
    for (int idx = threadIdx.x; idx < EV2 * EV3; idx += 256) wt[idx] = e3t[idx];
    __syncthreads();
    int r = blockIdx.x * 256 + threadIdx.x;
    if (r >= ROWS) return;
    float h3[EV3];
#pragma unroll
    for (int o3 = 0; o3 < EV3; o3++) h3[o3] = e3b[o3];
    for (int k = 0; k < EV2; k++) {
        float v = e2out[(size_t)r * EV2 + k];
#pragma unroll
        for (int o3 = 0; o3 < EV3; o3++) h3[o3] += v * wt[k * EV3 + o3];
    }
    float acc = e4b[0];
#pragma unroll
    for (int o3 = 0; o3 < EV3; o3++) acc += fmaxf(h3[o3], 0.f) * e4w[o3];
    out[r] = fmaxf(acc, 0.f);
}

// ---------------- host launch ----------------
extern "C" void kernel_launch(void* const* d_in, const int* in_sizes, int n_in,
                              void* d_out, int out_size, void* d_ws, size_t ws_size,
                              hipStream_t stream) {
    const float* x    = (const float*)d_in[0];
    const float* w_ih = (const float*)d_in[1];
    const float* w_hh = (const float*)d_in[2];
    const float* b_ih = (const float*)d_in[3];
    const float* b_hh = (const float*)d_in[4];
    const float* q1_w = (const float*)d_in[5];
    const float* q1_b = (const float*)d_in[6];
    const float* q2_w = (const float*)d_in[7];
    const float* q2_b = (const float*)d_in[8];
    const float* e1_w = (const float*)d_in[9];
    const float* e1_b = (const float*)d_in[10];
    const float* e2_w = (const float*)d_in[11];
    const float* e2_b = (const float*)d_in[12];
    const float* e3_w = (const float*)d_in[13];
    const float* e3_b = (const float*)d_in[14];
    const float* e4_w = (const float*)d_in[15];
    const float* e4_b = (const float*)d_in[16];
    float* out = (float*)d_out;
    float* ws = (float*)d_ws;

    // ---- workspace layout (float offsets) ----
    size_t off = 0;
    float* seq    = ws + off; off += (size_t)NN * BB * EE;   // 262,144
    size_t regionA = off; off += 23000000;
    short* wf       = (short*)(ws + regionA);                // 375*47*512 = 9,024,000 sh
    short* seq_p    = (short*)(ws + regionA + 4600000);      // 655,360 sh
    short* wih_p    = (short*)(ws + regionA + 5000000);      // 3,850,240 sh
    short* pairs_p  = (short*)(ws + regionA);                // 10,158,080 sh (bf16)
    short* q1out_p  = (short*)(ws + regionA + 10200000);     // 12,697,600 sh (bf16)
    short* e1out_p  = (short*)(ws + regionA);                // 20,316,160 sh (bf16)
    float* e2out    = ws + regionA + 20400000;               // 1,587,200 fl
    float* xgT    = ws + off; off += 7618560;                // 6,144,000 fl; q2out_p alias
    short* q2out_p  = (short*)xgT;                           // 7,618,560 sh (bf16)
    float* ht     = ws + off; off += BH;
    float* ct     = ws + off; off += BH;                     // ct + hbuf contiguous: one zero
    short* hbuf   = (short*)(ws + off); off += 48128;        // 2 x HSZ shorts (single plane)
    short* q1w_p  = (short*)(ws + off); off += 409600;       // single-plane
    short* q2w_p  = (short*)(ws + off); off += 291840;       // single-plane
    short* e1w_p  = (short*)(ws + off); off += 409600;       // single-plane
    short* e2w_p  = (short*)(ws + off); off += 163840;       // single-plane
    float* e1at   = ws + off; off += (size_t)HH * EV1;
    float* e3t    = ws + off; off += 1024;
    float* pb     = ws + off; off += BB * EV1;
    float* q1beff = ws + off; off += 1024;
    float* bsum   = ws + off; off += 6016;
    int*   iijj   = (int*)(ws + off); off += 1024;

    dim3 tb(32, 8);

    // init (ct and hbuf are contiguous -> single zero launch)
    k_iijj<<<1, 512, 0, stream>>>(iijj);
    k_q1beff<<<3, 256, 0, stream>>>(q1_w, q1_b, q1beff);
    k_addb<<<24, 256, 0, stream>>>(b_ih, b_hh, bsum, G4);
    k_zero<<<376, 256, 0, stream>>>(ct, BH + 48128);

    // weight transforms
    k_pack_wf<<<dim3(LKT, LBLK), 128, 0, stream>>>(w_hh, wf);
    k_transpose<<<dim3(47, 32), tb, 0, stream>>>(e1_w, e1at, EV1, HH + QO, 0, HH);
    k_transpose<<<dim3(4, 1), tb, 0, stream>>>(e3_w, e3t, EV3, EV2, 0, EV2);
    k_pack<<<dim3(8, 47), 256, 0, stream>>>(w_ih, EE, 0, G4, EE, wih_p);
    k_pack1<<<dim3(16, 5), 256, 0, stream>>>(q1_w, QIN, 0, Q1O, QIN, q1w_p);
    k_pack1<<<dim3(19, 3), 256, 0, stream>>>(q2_w, Q1O, 0, QO, Q1O, q2w_p);
    k_pack1<<<dim3(10, 8), 256, 0, stream>>>(e1_w, HH + QO, HH, EV1, QO, e1w_p);
    k_pack1<<<dim3(32, 1), 256, 0, stream>>>(e2_w, EV1, 0, EV2, EV1, e2w_p);

    // sort + pack seq; xgT = (w_ih @ seq^T) + bsum written DIRECTLY in [n][j][b]
    k_sort<<<32, 256, 0, stream>>>(x, seq);
    k_pack<<<dim3(8, 8), 256, 0, stream>>>(seq, EE, 0, 1024, EE, seq_p);
    k_gemm_t<2, 2, 1><<<8 * 8 * 6, 256, 0, stream>>>(wih_p, 8, seq_p, bsum, nullptr,
                                                     xgT, nullptr, 0, 6016, EE, 1024, 0, 1);

    // LSTM: 32 fused steps, double-buffered single-plane h (kernel-boundary coherence)
    for (int nstep = 0; nstep < NN; nstep++) {
        const short* hr = hbuf + (size_t)(nstep & 1) * HSZ;
        short* hw = hbuf + (size_t)((nstep + 1) & 1) * HSZ;
        k_lstm_step<<<LBLK, 512, 0, stream>>>(wf, hr, hw,
                                              xgT + (size_t)nstep * (G4 * BB), ct, ht,
                                              nstep == NN - 1);
    }

    // evaluator plan-side bias (includes e1_b)
    k_pb<<<dim3(4, BB), 256, 0, stream>>>(ht, e1at, e1_b, pb);

    // pair MLP (packed pipeline; pairs_p overwrites dead wf — after LSTM)
    k_pairs<<<7936, 256, 0, stream>>>(x, iijj, pairs_p);
    k_gemm_t<1, 1, 1><<<8 * 5 * 16, 256, 0, stream>>>(pairs_p, 16, q1w_p, q1beff, nullptr,
                                                      nullptr, q1out_p, 20, ROWS, QIN, Q1O, 1, 0);
    k_gemm_t<1, 1, 1><<<8 * 3 * 16, 256, 0, stream>>>(q1out_p, 20, q2w_p, q2_b, nullptr,
                                                      nullptr, q2out_p, 12, ROWS, Q1O, QO, 1, 0);
    k_gemm_t<1, 1, 1><<<8 * 8 * 16, 256, 0, stream>>>(q2out_p, 12, e1w_p, nullptr, pb,
                                                      nullptr, e1out_p, 32, ROWS, QO, EV1, 1, 0);
    k_gemm_t<1, 1, 1><<<8 * 1 * 16, 256, 0, stream>>>(e1out_p, 32, e2w_p, e2_b, nullptr,
                                                      e2out, nullptr, 0, ROWS, EV1, EV2, 1, 0);
    k_e34<<<62, 256, 0, stream>>>(e2out, e3t, e3_b, e4_w, e4_b, out);
}